// Round 1
// 221.502 us; speedup vs baseline: 1.0820x; 1.0820x over previous
//
#include <hip/hip_runtime.h>
#include <math.h>

// Problem constants
#define B_ 2
#define L_ 2048
#define S_ 2048
#define E_ 1024
#define H_ 16
#define D_ 64
#define SC_ 0.180336880111120f  // (1/sqrt(64)) * log2(e), folded into Q projection

typedef unsigned short u16;
typedef unsigned int u32;
typedef __attribute__((ext_vector_type(8))) short short8;    // 8 bf16 (4 VGPRs)
typedef __attribute__((ext_vector_type(4))) float floatx4;   // 16x16 accum

__device__ __forceinline__ u16 f2bf(float f) {
    union { float f; unsigned u; } a; a.f = f;
    unsigned r = a.u + 0x7FFFu + ((a.u >> 16) & 1u);  // RNE
    return (u16)(r >> 16);
}

// pack two f32 -> bf16x2 (RNE), single instruction
__device__ __forceinline__ u32 cvt_pk_bf16(float lo, float hi) {
    u32 d;
    asm("v_cvt_pk_bf16_f32 %0, %1, %2" : "=v"(d) : "v"(lo), "v"(hi));
    return d;
}

// cross-lane half-swaps (gfx950): both operands are read-write.
// P32: a' = [a0,a1,b0,b1], b' = [a2,a3,b2,b3]   (rows = 16-lane groups)
// P16: a' = [a0,b0,a2,b2], b' = [a1,b1,a3,b3]
__device__ __forceinline__ void pl32swap(u32& a, u32& b) {
    asm("v_permlane32_swap_b32 %0, %1" : "+v"(a), "+v"(b));
}
__device__ __forceinline__ void pl16swap(u32& a, u32& b) {
    asm("v_permlane16_swap_b32 %0, %1" : "+v"(a), "+v"(b));
}

// async global->LDS, 16B per lane; LDS dest = wave-uniform base + lane*16
__device__ __forceinline__ void glds16(const u16* g, u16* l) {
    __builtin_amdgcn_global_load_lds(
        (const __attribute__((address_space(1))) void*)g,
        (__attribute__((address_space(3))) void*)l, 16, 0, 0);
}

// ---------------------------------------------------------------------------
// f32 -> bf16 cast; grid.y selects (x->Xb, ctx->Cb)
// ---------------------------------------------------------------------------
__global__ void cast_bf16_kernel(const float* __restrict__ x, const float* __restrict__ ctx,
                                 u16* __restrict__ Xb, u16* __restrict__ Cb) {
    const float* src = blockIdx.y ? ctx : x;
    u16* dst = blockIdx.y ? Cb : Xb;
    int i = blockIdx.x * 256 + threadIdx.x;
    float4 u0 = ((const float4*)src)[2 * i];
    float4 u1 = ((const float4*)src)[2 * i + 1];
    uint4 o;
    o.x = cvt_pk_bf16(u0.x, u0.y);
    o.y = cvt_pk_bf16(u0.z, u0.w);
    o.z = cvt_pk_bf16(u1.x, u1.y);
    o.w = cvt_pk_bf16(u1.z, u1.w);
    ((uint4*)dst)[i] = o;
}

// ---------------------------------------------------------------------------
// Weight transpose+cast: Wt[n][k] = bf16(W[k][n]); grid.z selects weight
// ---------------------------------------------------------------------------
__global__ void transpose_cast_kernel(const float* __restrict__ Wq, const float* __restrict__ Wk,
                                      const float* __restrict__ Wv, const float* __restrict__ Wp,
                                      u16* __restrict__ WqT, u16* __restrict__ WkT,
                                      u16* __restrict__ WvT, u16* __restrict__ WpT) {
    const int z = blockIdx.z;
    const float* W = z == 0 ? Wq : (z == 1 ? Wk : (z == 2 ? Wv : Wp));
    u16* Wt = z == 0 ? WqT : (z == 1 ? WkT : (z == 2 ? WvT : WpT));
    __shared__ float tile[32][33];
    const int bx = blockIdx.x * 32, by = blockIdx.y * 32;
    const int tx = threadIdx.x, ty = threadIdx.y;  // block (32, 8)
#pragma unroll
    for (int j = 0; j < 4; ++j)
        tile[ty + j * 8][tx] = W[(size_t)(by + ty + j * 8) * E_ + bx + tx];
    __syncthreads();
#pragma unroll
    for (int j = 0; j < 4; ++j)
        Wt[(size_t)(bx + ty + j * 8) * E_ + by + tx] = f2bf(tile[tx][ty + j * 8]);
}

// ---------------------------------------------------------------------------
// XCD-aware block remap for (8 n-tiles) x (32 m-tiles) grids.
// ---------------------------------------------------------------------------
__device__ __forceinline__ void xcd_remap(int bx, int by, int& m_idx, int& n_idx) {
    int lin = bx + 8 * by;       // 0..255
    int c8 = lin & 7;            // ~XCD
    int g = lin >> 3;            // 0..31
    m_idx = c8 + 8 * (g & 3);    // 0..31 ; m_idx % 8 == c8
    n_idx = g >> 2;              // 0..7
}

// ---------------------------------------------------------------------------
// Fused QKV projection GEMM (unchanged): BM=128 BN=128 BK=64, 256 threads,
// double-buffered glds16, XOR-swizzled LDS, XCD remap.
// ---------------------------------------------------------------------------
__global__ __launch_bounds__(256, 2) void qkv_gemm_kernel(
    const u16* __restrict__ Xb, const u16* __restrict__ Cb,
    const u16* __restrict__ WqT, const u16* __restrict__ WkT, const u16* __restrict__ WvT,
    const float* __restrict__ bq, const float* __restrict__ bk, const float* __restrict__ bv,
    u16* __restrict__ Qb, u16* __restrict__ Kb, u16* __restrict__ Vtb) {
    __shared__ __align__(16) u16 As[2][128 * 64];  // 2 x 16 KB
    __shared__ __align__(16) u16 Bs[2][128 * 64];  // 2 x 16 KB

    const int z = blockIdx.z;
    const u16* A  = z == 0 ? Xb : Cb;
    const u16* Bt = z == 0 ? WqT : (z == 1 ? WkT : WvT);
    const float* bias = z == 0 ? bq : (z == 1 ? bk : bv);
    const float scale = z == 0 ? SC_ : 1.0f;

    const int tid = threadIdx.x;
    const int lane = tid & 63;
    const int wv = tid >> 6;
    const int wm = wv >> 1, wn = wv & 1;
    const int qd = lane >> 4, lr = lane & 15;
    int m_idx, n_idx;
    xcd_remap(blockIdx.x, blockIdx.y, m_idx, n_idx);
    const int m0 = m_idx * 128, n0 = n_idx * 128;
    const int lrow = lane >> 3;        // 0..7
    const int gu = (lane & 7) ^ lrow;  // swizzled global 16B-unit

    floatx4 acc[4][4];
#pragma unroll
    for (int i = 0; i < 4; ++i)
#pragma unroll
        for (int j = 0; j < 4; ++j) {
            floatx4 zz = {0.f, 0.f, 0.f, 0.f};
            acc[i][j] = zz;
        }

#define STAGE_AB(buf, kb)                                                          \
    {                                                                              \
        _Pragma("unroll") for (int j = 0; j < 4; ++j) {                            \
            int c = wv * 4 + j;                                                    \
            glds16(A + (size_t)(m0 + c * 8 + lrow) * E_ + (kb) + gu * 8,           \
                   &As[buf][c * 512]);                                             \
            glds16(Bt + (size_t)(n0 + c * 8 + lrow) * E_ + (kb) + gu * 8,          \
                   &Bs[buf][c * 512]);                                             \
        }                                                                          \
    }

    STAGE_AB(0, 0)
    __syncthreads();  // tile 0 landed (vmcnt drained at barrier)

    for (int t = 0; t < 16; ++t) {
        const int cur = t & 1;
        if (t + 1 < 16) STAGE_AB(cur ^ 1, (t + 1) * 64)

        short8 af[4][2], bf[4][2];
#pragma unroll
        for (int mi = 0; mi < 4; ++mi)
#pragma unroll
            for (int kk = 0; kk < 2; ++kk) {
                int row = wm * 64 + mi * 16 + lr;
                int u = (kk * 4 + qd) ^ (lr & 7);
                af[mi][kk] = *(const short8*)(&As[cur][row * 64 + u * 8]);
            }
#pragma unroll
        for (int ni = 0; ni < 4; ++ni)
#pragma unroll
            for (int kk = 0; kk < 2; ++kk) {
                int row = wn * 64 + ni * 16 + lr;
                int u = (kk * 4 + qd) ^ (lr & 7);
                bf[ni][kk] = *(const short8*)(&Bs[cur][row * 64 + u * 8]);
            }
#pragma unroll
        for (int kk = 0; kk < 2; ++kk)
#pragma unroll
            for (int mi = 0; mi < 4; ++mi)
#pragma unroll
                for (int ni = 0; ni < 4; ++ni)
                    acc[mi][ni] = __builtin_amdgcn_mfma_f32_16x16x32_bf16(
                        af[mi][kk], bf[ni][kk], acc[mi][ni], 0, 0, 0);

        __syncthreads();  // readers done with cur; prefetch into cur^1 drained
    }

    // epilogue: C/D row = qd*4+r, col = lane&15
    u16* Cq = z == 0 ? Qb : Kb;
#pragma unroll
    for (int mi = 0; mi < 4; ++mi) {
#pragma unroll
        for (int ni = 0; ni < 4; ++ni) {
            int col = n0 + wn * 64 + ni * 16 + lr;
            float bv_ = bias[col];
            if (z == 2) {
                int row0 = m0 + wm * 64 + mi * 16 + qd * 4;
                int bidx = row0 >> 11;
                int sloc = row0 & (S_ - 1);
                u16 h0 = f2bf(acc[mi][ni][0] + bv_);
                u16 h1 = f2bf(acc[mi][ni][1] + bv_);
                u16 h2 = f2bf(acc[mi][ni][2] + bv_);
                u16 h3 = f2bf(acc[mi][ni][3] + bv_);
                uint2 pk;
                pk.x = h0 | ((unsigned)h1 << 16);
                pk.y = h2 | ((unsigned)h3 << 16);
                *(uint2*)&Vtb[((size_t)(bidx * E_ + col)) * S_ + sloc] = pk;
            } else {
#pragma unroll
                for (int r = 0; r < 4; ++r) {
                    int row = m0 + wm * 64 + mi * 16 + qd * 4 + r;
                    Cq[(size_t)row * E_ + col] = f2bf((acc[mi][ni][r] + bv_) * scale);
                }
            }
        }
    }
#undef STAGE_AB
}

// ---------------------------------------------------------------------------
// Flash attention, in-register softmax (T12-style, 16x16 fragments):
// grid (L/128, B*H, 2), 256 threads (4 waves). Wave w owns Q rows
// [w*32, w*32+32). SWAPPED QK^T: S^T = mfma(K, Q) so each lane holds
// P[s-slice][q=lr] lane-locally. p = exp2(s'); cvt_pk -> bf16 pairs;
// 2x permlane swap rebuilds PV A-fragments in-register (no P LDS round
// trip, no Q LDS staging -> LDS = 32 KB -> 4 blocks/CU, zero grid tail).
// Fixed-reference softmax (M=0; scale folded into Q).
// Outputs: NORMALIZED O-partial (bf16) + l-partial (f32).
// ---------------------------------------------------------------------------
__global__ __launch_bounds__(256, 4) void flash_attn_kernel(
    const u16* __restrict__ Q, const u16* __restrict__ Kg,
    const u16* __restrict__ Vtg, u16* __restrict__ Opart, float* __restrict__ lpart) {
    __shared__ __align__(16) u16 Ks[2][64 * 64];  // 2 x 8 KB (swizzled)
    __shared__ __align__(16) u16 Vs[2][64 * 64];  // 2 x 8 KB, V^T layout [d][s]

    const int tid = threadIdx.x;
    const int lane = tid & 63;
    const int wv = tid >> 6;
    const int qd = lane >> 4, lr = lane & 15;
    const int b = blockIdx.y >> 4, h = blockIdx.y & 15;
    const int q0 = blockIdx.x * 128;
    const int z = blockIdx.z;
    const int sbeg = z * (S_ / 2);

    u16* Op = Opart + (size_t)z * (B_ * L_ * E_);
    float* lp = lpart + (size_t)z * (B_ * H_ * L_);

    const u16* Kbase = Kg + (size_t)(b * S_) * E_ + h * D_;
    const u16* Vbase = Vtg + (size_t)(b * E_ + h * D_) * S_;  // rows=d, cols=s

    const int lrow = lane >> 3;        // 0..7
    const int gu = (lane & 7) ^ lrow;  // swizzled global 16B-unit

    // issue K/V tile 0 loads first (in flight during Q fragment loads)
#pragma unroll
    for (int j = 0; j < 2; ++j) {
        int c = wv * 2 + j;
        glds16(Kbase + (size_t)(sbeg + c * 8 + lrow) * E_ + gu * 8, &Ks[0][c * 512]);
        glds16(Vbase + (size_t)(c * 8 + lrow) * S_ + sbeg + gu * 8, &Vs[0][c * 512]);
    }

    // Q fragments (B-operand: col=q=lr, k=d=kk*32+qd*8..+7) direct from global.
    // 16B-aligned contiguous per lane; one-time load, no LDS staging.
    short8 qf[2][2];
#pragma unroll
    for (int mi = 0; mi < 2; ++mi)
#pragma unroll
        for (int kk = 0; kk < 2; ++kk)
            qf[mi][kk] = *(const short8*)(Q + (size_t)(b * L_ + q0 + wv * 32 + mi * 16 + lr) * E_ +
                                          h * D_ + kk * 32 + qd * 8);

    floatx4 o_acc[2][4];
    float l_acc[2] = {0.f, 0.f};
#pragma unroll
    for (int mi = 0; mi < 2; ++mi)
#pragma unroll
        for (int nt = 0; nt < 4; ++nt) {
            floatx4 z4 = {0.f, 0.f, 0.f, 0.f};
            o_acc[mi][nt] = z4;
        }

    __syncthreads();  // K/V tile 0 landed

    const int NIT = (S_ / 2) / 64;  // 16

    for (int it = 0; it < NIT; ++it) {
        const int cur = it & 1;
        // prefetch next K/V tile into the other buffer (in flight during compute)
        if (it + 1 < NIT) {
            int s1 = sbeg + (it + 1) * 64;
#pragma unroll
            for (int j = 0; j < 2; ++j) {
                int c = wv * 2 + j;
                glds16(Kbase + (size_t)(s1 + c * 8 + lrow) * E_ + gu * 8, &Ks[cur ^ 1][c * 512]);
                glds16(Vbase + (size_t)(c * 8 + lrow) * S_ + s1 + gu * 8, &Vs[cur ^ 1][c * 512]);
            }
        }

        // ---- S'^T = K Q^T (swapped): D[s][q], lane holds q=lr, s=nt*16+qd*4+r ----
        floatx4 s_[2][4];
#pragma unroll
        for (int nt = 0; nt < 4; ++nt) {
            int krow = nt * 16 + lr;
            short8 kb0 = *(const short8*)(&Ks[cur][krow * 64 + ((qd) ^ (lr & 7)) * 8]);
            short8 kb1 = *(const short8*)(&Ks[cur][krow * 64 + ((4 + qd) ^ (lr & 7)) * 8]);
#pragma unroll
            for (int mi = 0; mi < 2; ++mi) {
                floatx4 zz = {0.f, 0.f, 0.f, 0.f};
                zz = __builtin_amdgcn_mfma_f32_16x16x32_bf16(kb0, qf[mi][0], zz, 0, 0, 0);
                zz = __builtin_amdgcn_mfma_f32_16x16x32_bf16(kb1, qf[mi][1], zz, 0, 0, 0);
                s_[mi][nt] = zz;
            }
        }

        // ---- p = exp2(s'); pack bf16 pairs; permlane exchange -> PV A-frags ----
        // dg[nt][i] at lane (qd_s,lr) = pk(P[s=nt*16+qd_s*4+2i .. +2i+1][q=lr]).
        // Target pf[kk] dword j at lane (qd_t,lr) = dg[2kk+(qd_t>>1)][j&1] from
        // lane 16*(2*(qd_t&1)+(j>>1))+lr  ==  P32 then P16 swap (derived, see top).
        short8 pf[2][2];
#pragma unroll
        for (int mi = 0; mi < 2; ++mi) {
            u32 dg[4][2];
            float ls = 0.f;
#pragma unroll
            for (int nt = 0; nt < 4; ++nt) {
                float p0 = __builtin_amdgcn_exp2f(s_[mi][nt][0]);
                float p1 = __builtin_amdgcn_exp2f(s_[mi][nt][1]);
                float p2 = __builtin_amdgcn_exp2f(s_[mi][nt][2]);
                float p3 = __builtin_amdgcn_exp2f(s_[mi][nt][3]);
                ls += (p0 + p1) + (p2 + p3);
                dg[nt][0] = cvt_pk_bf16(p0, p1);
                dg[nt][1] = cvt_pk_bf16(p2, p3);
            }
            l_acc[mi] += ls;
#pragma unroll
            for (int kk = 0; kk < 2; ++kk) {
                u32 x0 = dg[2 * kk][0], y0 = dg[2 * kk + 1][0];
                pl32swap(x0, y0);  // x0=[X0,X1,Y0,Y1] y0=[X2,X3,Y2,Y3]
                pl16swap(x0, y0);  // x0=[X0,X2,Y0,Y2] y0=[X1,X3,Y1,Y3]
                u32 x1 = dg[2 * kk][1], y1 = dg[2 * kk + 1][1];
                pl32swap(x1, y1);
                pl16swap(x1, y1);
                union { u32 d[4]; short8 v; } u;
                u.d[0] = x0; u.d[1] = x1; u.d[2] = y0; u.d[3] = y1;
                pf[mi][kk] = u.v;
            }
        }

        // ---- O += P V ----
#pragma unroll
        for (int nt = 0; nt < 4; ++nt) {
            int vrow = nt * 16 + lr;
            short8 vb0 = *(const short8*)(&Vs[cur][vrow * 64 + ((qd) ^ (lr & 7)) * 8]);
            short8 vb1 = *(const short8*)(&Vs[cur][vrow * 64 + ((4 + qd) ^ (lr & 7)) * 8]);
#pragma unroll
            for (int mi = 0; mi < 2; ++mi) {
                o_acc[mi][nt] = __builtin_amdgcn_mfma_f32_16x16x32_bf16(pf[mi][0], vb0, o_acc[mi][nt], 0, 0, 0);
                o_acc[mi][nt] = __builtin_amdgcn_mfma_f32_16x16x32_bf16(pf[mi][1], vb1, o_acc[mi][nt], 0, 0, 0);
            }
        }

        __syncthreads();  // readers done with cur; prefetch into cur^1 drained
    }

    // ---- epilogue: l reduction over qd-lane group; write l + normalized O ----
    float linv[2][4];
#pragma unroll
    for (int mi = 0; mi < 2; ++mi) {
        float l = l_acc[mi];
        l += __shfl_xor(l, 16);
        l += __shfl_xor(l, 32);  // lanes {lr, lr+16, lr+32, lr+48} summed: row q=lr
        if (lane < 16)
            lp[(size_t)(b * H_ + h) * L_ + q0 + wv * 32 + mi * 16 + lane] = l;
        float il = 1.0f / l;
#pragma unroll
        for (int r = 0; r < 4; ++r) linv[mi][r] = __shfl(il, qd * 4 + r);
    }

#pragma unroll
    for (int mi = 0; mi < 2; ++mi)
#pragma unroll
        for (int nt = 0; nt < 4; ++nt)
#pragma unroll
            for (int r = 0; r < 4; ++r) {
                int row = q0 + wv * 32 + mi * 16 + qd * 4 + r;
                int col = h * D_ + nt * 16 + lr;
                Op[(size_t)(b * L_ + row) * E_ + col] = f2bf(o_acc[mi][nt][r] * linv[mi][r]);
            }
}

// ---------------------------------------------------------------------------
// Output GEMM with fused split-S combine (unchanged).
// ---------------------------------------------------------------------------
__global__ __launch_bounds__(256, 2) void out_gemm_kernel(
    const u16* __restrict__ O1, const u16* __restrict__ O2,
    const float* __restrict__ l1, const float* __restrict__ l2,
    const u16* __restrict__ WpT, const float* __restrict__ bp,
    float* __restrict__ out) {
    __shared__ __align__(16) u16 As[2][128 * 64];
    __shared__ __align__(16) u16 Bs[2][128 * 64];

    const int tid = threadIdx.x;
    const int lane = tid & 63;
    const int wv = tid >> 6;
    const int wm = wv >> 1, wn = wv & 1;
    const int qd = lane >> 4, lr = lane & 15;
    int m_idx, n_idx;
    xcd_remap(blockIdx.x, blockIdx.y, m_idx, n_idx);
    const int m0 = m_idx * 128, n0 = n_idx * 128;
    const int lrow = lane >> 3;
    const int gu = (lane & 7) ^ lrow;

    floatx4 acc[4][4];
#pragma unroll
    for (int i = 0; i < 4; ++i)
#pragma unroll
        for (int j = 0; j < 4; ++j) {
            floatx4 zz = {0.f, 0.f, 0.f, 0.f};
            acc[i][j] = zz;
        }

    uint4 p1[4], p2[4];
    float la_[4], lb_[4];

#define LOAD_AO(tt)                                                                \
    {                                                                              \
        _Pragma("unroll") for (int j = 0; j < 4; ++j) {                            \
            int c = wv * 4 + j;                                                    \
            int row = m0 + c * 8 + lrow;                                           \
            int col = (tt)*64 + gu * 8;                                            \
            p1[j] = *(const uint4*)(O1 + (size_t)row * E_ + col);                  \
            p2[j] = *(const uint4*)(O2 + (size_t)row * E_ + col);                  \
            int li = (row >> 11) * (H_ * L_) + (tt)*L_ + (row & (L_ - 1));         \
            la_[j] = l1[li];                                                       \
            lb_[j] = l2[li];                                                       \
        }                                                                          \
    }

#define WRITE_AO(buf)                                                              \
    {                                                                              \
        _Pragma("unroll") for (int j = 0; j < 4; ++j) {                            \
            int c = wv * 4 + j;                                                    \
            float s = 1.0f / (la_[j] + lb_[j]);                                    \
            float w1 = la_[j] * s, w2 = lb_[j] * s;                                \
            const u32* pa = (const u32*)&p1[j];                                    \
            const u32* pb = (const u32*)&p2[j];                                    \
            uint4 o;                                                               \
            u32* po = (u32*)&o;                                                    \
            _Pragma("unroll") for (int d = 0; d < 4; ++d) {                        \
                union { u32 u; float f; } x0, x1, y0, y1;                          \
                x0.u = pa[d] << 16; x1.u = pa[d] & 0xFFFF0000u;                    \
                y0.u = pb[d] << 16; y1.u = pb[d] & 0xFFFF0000u;                    \
                po[d] = cvt_pk_bf16(x0.f * w1 + y0.f * w2, x1.f * w1 + y1.f * w2); \
            }                                                                      \
            *(uint4*)(&As[buf][c * 512 + lane * 8]) = o;                           \
        }                                                                          \
    }

#define STAGE_BO(buf, kb)                                                          \
    {                                                                              \
        _Pragma("unroll") for (int j = 0; j < 4; ++j) {                            \
            int c = wv * 4 + j;                                                    \
            glds16(WpT + (size_t)(n0 + c * 8 + lrow) * E_ + (kb) + gu * 8,         \
                   &Bs[buf][c * 512]);                                             \
        }                                                                          \
    }

    LOAD_AO(0)
    STAGE_BO(0, 0)
    WRITE_AO(0)
    __syncthreads();

    for (int t = 0; t < 16; ++t) {
        const int cur = t & 1;
        if (t + 1 < 16) {
            STAGE_BO(cur ^ 1, (t + 1) * 64)
            LOAD_AO(t + 1)
        }

        short8 af[4][2], bf[4][2];
#pragma unroll
        for (int mi = 0; mi < 4; ++mi)
#pragma unroll
            for (int kk = 0; kk < 2; ++kk) {
                int row = wm * 64 + mi * 16 + lr;
                int u = (kk * 4 + qd) ^ (lr & 7);
                af[mi][kk] = *(const short8*)(&As[cur][row * 64 + u * 8]);
            }
#pragma unroll
        for (int ni = 0; ni < 4; ++ni)
#pragma unroll
            for (int kk = 0; kk < 2; ++kk) {
                int row = wn * 64 + ni * 16 + lr;
                int u = (kk * 4 + qd) ^ (lr & 7);
                bf[ni][kk] = *(const short8*)(&Bs[cur][row * 64 + u * 8]);
            }
#pragma unroll
        for (int kk = 0; kk < 2; ++kk)
#pragma unroll
            for (int mi = 0; mi < 4; ++mi)
#pragma unroll
                for (int ni = 0; ni < 4; ++ni)
                    acc[mi][ni] = __builtin_amdgcn_mfma_f32_16x16x32_bf16(
                        af[mi][kk], bf[ni][kk], acc[mi][ni], 0, 0, 0);

        if (t + 1 < 16) WRITE_AO(cur ^ 1)
        __syncthreads();
    }

#pragma unroll
    for (int mi = 0; mi < 4; ++mi)
#pragma unroll
        for (int ni = 0; ni < 4; ++ni) {
            int col = n0 + wn * 64 + ni * 16 + lr;
            float bv_ = bp[col];
#pragma unroll
            for (int r = 0; r < 4; ++r) {
                int row = m0 + wm * 64 + mi * 16 + qd * 4 + r;
                out[(size_t)row * E_ + col] = acc[mi][ni][r] + bv_;
            }
        }
#undef LOAD_AO
#undef WRITE_AO
#undef STAGE_BO
}

// ---------------------------------------------------------------------------
extern "C" void kernel_launch(void* const* d_in, const int* in_sizes, int n_in,
                              void* d_out, int out_size, void* d_ws, size_t ws_size,
                              hipStream_t stream) {
    const float* x   = (const float*)d_in[0];
    const float* ctx = (const float*)d_in[1];
    const float* Wq  = (const float*)d_in[2];
    const float* bq  = (const float*)d_in[3];
    const float* Wk  = (const float*)d_in[4];
    const float* bk  = (const float*)d_in[5];
    const float* Wv  = (const float*)d_in[6];
    const float* bv  = (const float*)d_in[7];
    const float* Wp  = (const float*)d_in[8];
    const float* bp  = (const float*)d_in[9];
    float* out = (float*)d_out;

    // workspace (u16 elems): WqT..WpT 4x1M | Qb 4M | Kb 4M | Vtb 4M |
    // Xb 4M | Cb 4M (Xb/Cb reused as Opart[0/1] after projections) | lpart
    u16* WqT = (u16*)d_ws;
    u16* WkT = WqT + 1048576;
    u16* WvT = WkT + 1048576;
    u16* WpT = WvT + 1048576;
    u16* Qb  = WpT + 1048576;
    u16* Kb  = Qb + 4194304;
    u16* Vtb = Kb + 4194304;
    u16* Xb  = Vtb + 4194304;
    u16* Cb  = Xb + 4194304;
    u16* Opart = Xb;  // overlays Xb/Cb (dead after projections)
    float* lpart = (float*)(Cb + 4194304);
    (void)ws_size; (void)in_sizes; (void)n_in; (void)out_size;

    cast_bf16_kernel<<<dim3(2048, 2), 256, 0, stream>>>(x, ctx, Xb, Cb);
    transpose_cast_kernel<<<dim3(32, 32, 4), dim3(32, 8), 0, stream>>>(
        Wq, Wk, Wv, Wp, WqT, WkT, WvT, WpT);

    qkv_gemm_kernel<<<dim3(8, 32, 3), 256, 0, stream>>>(
        Xb, Cb, WqT, WkT, WvT, bq, bk, bv, Qb, Kb, Vtb);

    flash_attn_kernel<<<dim3(L_ / 128, B_ * H_, 2), 256, 0, stream>>>(
        Qb, Kb, Vtb, Opart, lpart);

    out_gemm_kernel<<<dim3(8, 32), 256, 0, stream>>>(
        Opart, Opart + 4194304, lpart, lpart + B_ * H_ * L_, WpT, bp, out);
}

// Round 2
// 216.259 us; speedup vs baseline: 1.1083x; 1.0242x over previous
//
#include <hip/hip_runtime.h>
#include <math.h>

// Problem constants
#define B_ 2
#define L_ 2048
#define S_ 2048
#define E_ 1024
#define H_ 16
#define D_ 64
#define SC_ 0.180336880111120f  // (1/sqrt(64)) * log2(e), folded into Q projection

typedef unsigned short u16;
typedef unsigned int u32;
typedef __attribute__((ext_vector_type(8))) short short8;    // 8 bf16 (4 VGPRs)
typedef __attribute__((ext_vector_type(4))) float floatx4;   // 16x16 accum

__device__ __forceinline__ u16 f2bf(float f) {
    union { float f; unsigned u; } a; a.f = f;
    unsigned r = a.u + 0x7FFFu + ((a.u >> 16) & 1u);  // RNE
    return (u16)(r >> 16);
}

// pack two f32 -> bf16x2 (RNE), single instruction
__device__ __forceinline__ u32 cvt_pk_bf16(float lo, float hi) {
    u32 d;
    asm("v_cvt_pk_bf16_f32 %0, %1, %2" : "=v"(d) : "v"(lo), "v"(hi));
    return d;
}

// cross-lane half-swaps (gfx950): both operands are read-write.
// P32: a' = [a0,a1,b0,b1], b' = [a2,a3,b2,b3]   (rows = 16-lane groups)
// P16: a' = [a0,b0,a2,b2], b' = [a1,b1,a3,b3]
__device__ __forceinline__ void pl32swap(u32& a, u32& b) {
    asm("v_permlane32_swap_b32 %0, %1" : "+v"(a), "+v"(b));
}
__device__ __forceinline__ void pl16swap(u32& a, u32& b) {
    asm("v_permlane16_swap_b32 %0, %1" : "+v"(a), "+v"(b));
}

// async global->LDS, 16B per lane; LDS dest = wave-uniform base + lane*16
__device__ __forceinline__ void glds16(const u16* g, u16* l) {
    __builtin_amdgcn_global_load_lds(
        (const __attribute__((address_space(1))) void*)g,
        (__attribute__((address_space(3))) void*)l, 16, 0, 0);
}

// ---------------------------------------------------------------------------
// f32 -> bf16 cast; grid.y selects (x->Xb, ctx->Cb)
// ---------------------------------------------------------------------------
__global__ void cast_bf16_kernel(const float* __restrict__ x, const float* __restrict__ ctx,
                                 u16* __restrict__ Xb, u16* __restrict__ Cb) {
    const float* src = blockIdx.y ? ctx : x;
    u16* dst = blockIdx.y ? Cb : Xb;
    int i = blockIdx.x * 256 + threadIdx.x;
    float4 u0 = ((const float4*)src)[2 * i];
    float4 u1 = ((const float4*)src)[2 * i + 1];
    uint4 o;
    o.x = cvt_pk_bf16(u0.x, u0.y);
    o.y = cvt_pk_bf16(u0.z, u0.w);
    o.z = cvt_pk_bf16(u1.x, u1.y);
    o.w = cvt_pk_bf16(u1.z, u1.w);
    ((uint4*)dst)[i] = o;
}

// ---------------------------------------------------------------------------
// Weight transpose+cast: Wt[n][k] = bf16(W[k][n]); grid.z selects weight
// ---------------------------------------------------------------------------
__global__ void transpose_cast_kernel(const float* __restrict__ Wq, const float* __restrict__ Wk,
                                      const float* __restrict__ Wv, const float* __restrict__ Wp,
                                      u16* __restrict__ WqT, u16* __restrict__ WkT,
                                      u16* __restrict__ WvT, u16* __restrict__ WpT) {
    const int z = blockIdx.z;
    const float* W = z == 0 ? Wq : (z == 1 ? Wk : (z == 2 ? Wv : Wp));
    u16* Wt = z == 0 ? WqT : (z == 1 ? WkT : (z == 2 ? WvT : WpT));
    __shared__ float tile[32][33];
    const int bx = blockIdx.x * 32, by = blockIdx.y * 32;
    const int tx = threadIdx.x, ty = threadIdx.y;  // block (32, 8)
#pragma unroll
    for (int j = 0; j < 4; ++j)
        tile[ty + j * 8][tx] = W[(size_t)(by + ty + j * 8) * E_ + bx + tx];
    __syncthreads();
#pragma unroll
    for (int j = 0; j < 4; ++j)
        Wt[(size_t)(bx + ty + j * 8) * E_ + by + tx] = f2bf(tile[tx][ty + j * 8]);
}

// ---------------------------------------------------------------------------
// XCD-aware block remap for (8 n-tiles) x (32 m-tiles) grids.
// ---------------------------------------------------------------------------
__device__ __forceinline__ void xcd_remap(int bx, int by, int& m_idx, int& n_idx) {
    int lin = bx + 8 * by;       // 0..255
    int c8 = lin & 7;            // ~XCD
    int g = lin >> 3;            // 0..31
    m_idx = c8 + 8 * (g & 3);    // 0..31 ; m_idx % 8 == c8
    n_idx = g >> 2;              // 0..7
}

// ---------------------------------------------------------------------------
// Fused QKV projection GEMM (unchanged): BM=128 BN=128 BK=64, 256 threads,
// double-buffered glds16, XOR-swizzled LDS, XCD remap.
// ---------------------------------------------------------------------------
__global__ __launch_bounds__(256, 2) void qkv_gemm_kernel(
    const u16* __restrict__ Xb, const u16* __restrict__ Cb,
    const u16* __restrict__ WqT, const u16* __restrict__ WkT, const u16* __restrict__ WvT,
    const float* __restrict__ bq, const float* __restrict__ bk, const float* __restrict__ bv,
    u16* __restrict__ Qb, u16* __restrict__ Kb, u16* __restrict__ Vtb) {
    __shared__ __align__(16) u16 As[2][128 * 64];  // 2 x 16 KB
    __shared__ __align__(16) u16 Bs[2][128 * 64];  // 2 x 16 KB

    const int z = blockIdx.z;
    const u16* A  = z == 0 ? Xb : Cb;
    const u16* Bt = z == 0 ? WqT : (z == 1 ? WkT : WvT);
    const float* bias = z == 0 ? bq : (z == 1 ? bk : bv);
    const float scale = z == 0 ? SC_ : 1.0f;

    const int tid = threadIdx.x;
    const int lane = tid & 63;
    const int wv = tid >> 6;
    const int wm = wv >> 1, wn = wv & 1;
    const int qd = lane >> 4, lr = lane & 15;
    int m_idx, n_idx;
    xcd_remap(blockIdx.x, blockIdx.y, m_idx, n_idx);
    const int m0 = m_idx * 128, n0 = n_idx * 128;
    const int lrow = lane >> 3;        // 0..7
    const int gu = (lane & 7) ^ lrow;  // swizzled global 16B-unit

    floatx4 acc[4][4];
#pragma unroll
    for (int i = 0; i < 4; ++i)
#pragma unroll
        for (int j = 0; j < 4; ++j) {
            floatx4 zz = {0.f, 0.f, 0.f, 0.f};
            acc[i][j] = zz;
        }

#define STAGE_AB(buf, kb)                                                          \
    {                                                                              \
        _Pragma("unroll") for (int j = 0; j < 4; ++j) {                            \
            int c = wv * 4 + j;                                                    \
            glds16(A + (size_t)(m0 + c * 8 + lrow) * E_ + (kb) + gu * 8,           \
                   &As[buf][c * 512]);                                             \
            glds16(Bt + (size_t)(n0 + c * 8 + lrow) * E_ + (kb) + gu * 8,          \
                   &Bs[buf][c * 512]);                                             \
        }                                                                          \
    }

    STAGE_AB(0, 0)
    __syncthreads();  // tile 0 landed (vmcnt drained at barrier)

    for (int t = 0; t < 16; ++t) {
        const int cur = t & 1;
        if (t + 1 < 16) STAGE_AB(cur ^ 1, (t + 1) * 64)

        short8 af[4][2], bf[4][2];
#pragma unroll
        for (int mi = 0; mi < 4; ++mi)
#pragma unroll
            for (int kk = 0; kk < 2; ++kk) {
                int row = wm * 64 + mi * 16 + lr;
                int u = (kk * 4 + qd) ^ (lr & 7);
                af[mi][kk] = *(const short8*)(&As[cur][row * 64 + u * 8]);
            }
#pragma unroll
        for (int ni = 0; ni < 4; ++ni)
#pragma unroll
            for (int kk = 0; kk < 2; ++kk) {
                int row = wn * 64 + ni * 16 + lr;
                int u = (kk * 4 + qd) ^ (lr & 7);
                bf[ni][kk] = *(const short8*)(&Bs[cur][row * 64 + u * 8]);
            }
        __builtin_amdgcn_s_setprio(1);
#pragma unroll
        for (int kk = 0; kk < 2; ++kk)
#pragma unroll
            for (int mi = 0; mi < 4; ++mi)
#pragma unroll
                for (int ni = 0; ni < 4; ++ni)
                    acc[mi][ni] = __builtin_amdgcn_mfma_f32_16x16x32_bf16(
                        af[mi][kk], bf[ni][kk], acc[mi][ni], 0, 0, 0);
        __builtin_amdgcn_s_setprio(0);

        __syncthreads();  // readers done with cur; prefetch into cur^1 drained
    }

    // epilogue: C/D row = qd*4+r, col = lane&15
    u16* Cq = z == 0 ? Qb : Kb;
#pragma unroll
    for (int mi = 0; mi < 4; ++mi) {
#pragma unroll
        for (int ni = 0; ni < 4; ++ni) {
            int col = n0 + wn * 64 + ni * 16 + lr;
            float bv_ = bias[col];
            if (z == 2) {
                int row0 = m0 + wm * 64 + mi * 16 + qd * 4;
                int bidx = row0 >> 11;
                int sloc = row0 & (S_ - 1);
                u16 h0 = f2bf(acc[mi][ni][0] + bv_);
                u16 h1 = f2bf(acc[mi][ni][1] + bv_);
                u16 h2 = f2bf(acc[mi][ni][2] + bv_);
                u16 h3 = f2bf(acc[mi][ni][3] + bv_);
                uint2 pk;
                pk.x = h0 | ((unsigned)h1 << 16);
                pk.y = h2 | ((unsigned)h3 << 16);
                *(uint2*)&Vtb[((size_t)(bidx * E_ + col)) * S_ + sloc] = pk;
            } else {
#pragma unroll
                for (int r = 0; r < 4; ++r) {
                    int row = m0 + wm * 64 + mi * 16 + qd * 4 + r;
                    Cq[(size_t)row * E_ + col] = f2bf((acc[mi][ni][r] + bv_) * scale);
                }
            }
        }
    }
#undef STAGE_AB
}

// ---------------------------------------------------------------------------
// Flash attention, in-register softmax + XCD-group remap:
// grid (L/128, B*H, 2), 256 threads (4 waves). All 16 q-blocks of one
// (b,h,z) group are mapped to the SAME XCD (lin&7 ~ XCD, round-robin
// dispatch), so the group's K/V slice (256 KB) is fetched from HBM once
// and served from that XCD's L2 thereafter (8 groups x 256 KB = 2 MB of
// 4 MB L2). This converts the per-iter prefetch burst from ~900-cy HBM
// round-trips into ~200-cy L2 hits, which the compute phase covers.
// SWAPPED QK^T (S^T = mfma(K,Q)) keeps softmax fully in-register; P is
// rebuilt into PV A-fragments via cvt_pk + permlane swaps (no LDS P).
// Fixed-reference softmax (M=0; scale folded into Q).
// Outputs: NORMALIZED O-partial (bf16) + l-partial (f32).
// ---------------------------------------------------------------------------
__global__ __launch_bounds__(256, 4) void flash_attn_kernel(
    const u16* __restrict__ Q, const u16* __restrict__ Kg,
    const u16* __restrict__ Vtg, u16* __restrict__ Opart, float* __restrict__ lpart) {
    __shared__ __align__(16) u16 Ks[2][64 * 64];  // 2 x 8 KB (swizzled)
    __shared__ __align__(16) u16 Vs[2][64 * 64];  // 2 x 8 KB, V^T layout [d][s]

    const int tid = threadIdx.x;
    const int lane = tid & 63;
    const int wv = tid >> 6;
    const int qd = lane >> 4, lr = lane & 15;

    // XCD-group remap: lin = dispatch linear id; lin&7 ~ XCD.
    // qx = (lin>>3)&15, grp = (lin&7) + 8*(lin>>7)  (bijective, 1024 blocks)
    // -> XCD c owns groups {c, c+8, ..., c+56}, each with all 16 q-tiles.
    const int lin = blockIdx.x + 16 * (blockIdx.y + 32 * blockIdx.z);
    const int c8 = lin & 7;
    const int slot = lin >> 3;            // 0..127
    const int qx = slot & 15;             // q-tile index
    const int grp = c8 + 8 * (slot >> 4); // 0..63 = (bh, z)
    const int bh = grp & 31;
    const int z = grp >> 5;
    const int b = bh >> 4, h = bh & 15;
    const int q0 = qx * 128;
    const int sbeg = z * (S_ / 2);

    u16* Op = Opart + (size_t)z * (B_ * L_ * E_);
    float* lp = lpart + (size_t)z * (B_ * H_ * L_);

    const u16* Kbase = Kg + (size_t)(b * S_) * E_ + h * D_;
    const u16* Vbase = Vtg + (size_t)(b * E_ + h * D_) * S_;  // rows=d, cols=s

    const int lrow = lane >> 3;        // 0..7
    const int gu = (lane & 7) ^ lrow;  // swizzled global 16B-unit

    // issue K/V tile 0 loads first (in flight during Q fragment loads)
#pragma unroll
    for (int j = 0; j < 2; ++j) {
        int c = wv * 2 + j;
        glds16(Kbase + (size_t)(sbeg + c * 8 + lrow) * E_ + gu * 8, &Ks[0][c * 512]);
        glds16(Vbase + (size_t)(c * 8 + lrow) * S_ + sbeg + gu * 8, &Vs[0][c * 512]);
    }

    // Q fragments (B-operand: col=q=lr, k=d=kk*32+qd*8..+7) direct from global.
    short8 qf[2][2];
#pragma unroll
    for (int mi = 0; mi < 2; ++mi)
#pragma unroll
        for (int kk = 0; kk < 2; ++kk)
            qf[mi][kk] = *(const short8*)(Q + (size_t)(b * L_ + q0 + wv * 32 + mi * 16 + lr) * E_ +
                                          h * D_ + kk * 32 + qd * 8);

    floatx4 o_acc[2][4];
    float l_acc[2] = {0.f, 0.f};
#pragma unroll
    for (int mi = 0; mi < 2; ++mi)
#pragma unroll
        for (int nt = 0; nt < 4; ++nt) {
            floatx4 z4 = {0.f, 0.f, 0.f, 0.f};
            o_acc[mi][nt] = z4;
        }

    __syncthreads();  // K/V tile 0 landed

    const int NIT = (S_ / 2) / 64;  // 16

    for (int it = 0; it < NIT; ++it) {
        const int cur = it & 1;
        // prefetch next K/V tile into the other buffer (in flight during compute)
        if (it + 1 < NIT) {
            int s1 = sbeg + (it + 1) * 64;
#pragma unroll
            for (int j = 0; j < 2; ++j) {
                int c = wv * 2 + j;
                glds16(Kbase + (size_t)(s1 + c * 8 + lrow) * E_ + gu * 8, &Ks[cur ^ 1][c * 512]);
                glds16(Vbase + (size_t)(c * 8 + lrow) * S_ + s1 + gu * 8, &Vs[cur ^ 1][c * 512]);
            }
        }

        // ---- S'^T = K Q^T (swapped): D[s][q], lane holds q=lr, s=nt*16+qd*4+r ----
        floatx4 s_[2][4];
        __builtin_amdgcn_s_setprio(1);
#pragma unroll
        for (int nt = 0; nt < 4; ++nt) {
            int krow = nt * 16 + lr;
            short8 kb0 = *(const short8*)(&Ks[cur][krow * 64 + ((qd) ^ (lr & 7)) * 8]);
            short8 kb1 = *(const short8*)(&Ks[cur][krow * 64 + ((4 + qd) ^ (lr & 7)) * 8]);
#pragma unroll
            for (int mi = 0; mi < 2; ++mi) {
                floatx4 zz = {0.f, 0.f, 0.f, 0.f};
                zz = __builtin_amdgcn_mfma_f32_16x16x32_bf16(kb0, qf[mi][0], zz, 0, 0, 0);
                zz = __builtin_amdgcn_mfma_f32_16x16x32_bf16(kb1, qf[mi][1], zz, 0, 0, 0);
                s_[mi][nt] = zz;
            }
        }
        __builtin_amdgcn_s_setprio(0);

        // ---- p = exp2(s'); pack bf16 pairs; permlane exchange -> PV A-frags ----
        short8 pf[2][2];
#pragma unroll
        for (int mi = 0; mi < 2; ++mi) {
            u32 dg[4][2];
            float ls = 0.f;
#pragma unroll
            for (int nt = 0; nt < 4; ++nt) {
                float p0 = __builtin_amdgcn_exp2f(s_[mi][nt][0]);
                float p1 = __builtin_amdgcn_exp2f(s_[mi][nt][1]);
                float p2 = __builtin_amdgcn_exp2f(s_[mi][nt][2]);
                float p3 = __builtin_amdgcn_exp2f(s_[mi][nt][3]);
                ls += (p0 + p1) + (p2 + p3);
                dg[nt][0] = cvt_pk_bf16(p0, p1);
                dg[nt][1] = cvt_pk_bf16(p2, p3);
            }
            l_acc[mi] += ls;
#pragma unroll
            for (int kk = 0; kk < 2; ++kk) {
                u32 x0 = dg[2 * kk][0], y0 = dg[2 * kk + 1][0];
                pl32swap(x0, y0);  // x0=[X0,X1,Y0,Y1] y0=[X2,X3,Y2,Y3]
                pl16swap(x0, y0);  // x0=[X0,X2,Y0,Y2] y0=[X1,X3,Y1,Y3]
                u32 x1 = dg[2 * kk][1], y1 = dg[2 * kk + 1][1];
                pl32swap(x1, y1);
                pl16swap(x1, y1);
                union { u32 d[4]; short8 v; } u;
                u.d[0] = x0; u.d[1] = x1; u.d[2] = y0; u.d[3] = y1;
                pf[mi][kk] = u.v;
            }
        }

        // ---- O += P V ----
        __builtin_amdgcn_s_setprio(1);
#pragma unroll
        for (int nt = 0; nt < 4; ++nt) {
            int vrow = nt * 16 + lr;
            short8 vb0 = *(const short8*)(&Vs[cur][vrow * 64 + ((qd) ^ (lr & 7)) * 8]);
            short8 vb1 = *(const short8*)(&Vs[cur][vrow * 64 + ((4 + qd) ^ (lr & 7)) * 8]);
#pragma unroll
            for (int mi = 0; mi < 2; ++mi) {
                o_acc[mi][nt] = __builtin_amdgcn_mfma_f32_16x16x32_bf16(pf[mi][0], vb0, o_acc[mi][nt], 0, 0, 0);
                o_acc[mi][nt] = __builtin_amdgcn_mfma_f32_16x16x32_bf16(pf[mi][1], vb1, o_acc[mi][nt], 0, 0, 0);
            }
        }
        __builtin_amdgcn_s_setprio(0);

        __syncthreads();  // readers done with cur; prefetch into cur^1 drained
    }

    // ---- epilogue: l reduction over qd-lane group; write l + normalized O ----
    float linv[2][4];
#pragma unroll
    for (int mi = 0; mi < 2; ++mi) {
        float l = l_acc[mi];
        l += __shfl_xor(l, 16);
        l += __shfl_xor(l, 32);  // lanes {lr, lr+16, lr+32, lr+48} summed: row q=lr
        if (lane < 16)
            lp[(size_t)(b * H_ + h) * L_ + q0 + wv * 32 + mi * 16 + lane] = l;
        float il = 1.0f / l;
#pragma unroll
        for (int r = 0; r < 4; ++r) linv[mi][r] = __shfl(il, qd * 4 + r);
    }

#pragma unroll
    for (int mi = 0; mi < 2; ++mi)
#pragma unroll
        for (int nt = 0; nt < 4; ++nt)
#pragma unroll
            for (int r = 0; r < 4; ++r) {
                int row = q0 + wv * 32 + mi * 16 + qd * 4 + r;
                int col = h * D_ + nt * 16 + lr;
                Op[(size_t)(b * L_ + row) * E_ + col] = f2bf(o_acc[mi][nt][r] * linv[mi][r]);
            }
}

// ---------------------------------------------------------------------------
// Output GEMM with fused split-S combine (unchanged).
// ---------------------------------------------------------------------------
__global__ __launch_bounds__(256, 2) void out_gemm_kernel(
    const u16* __restrict__ O1, const u16* __restrict__ O2,
    const float* __restrict__ l1, const float* __restrict__ l2,
    const u16* __restrict__ WpT, const float* __restrict__ bp,
    float* __restrict__ out) {
    __shared__ __align__(16) u16 As[2][128 * 64];
    __shared__ __align__(16) u16 Bs[2][128 * 64];

    const int tid = threadIdx.x;
    const int lane = tid & 63;
    const int wv = tid >> 6;
    const int wm = wv >> 1, wn = wv & 1;
    const int qd = lane >> 4, lr = lane & 15;
    int m_idx, n_idx;
    xcd_remap(blockIdx.x, blockIdx.y, m_idx, n_idx);
    const int m0 = m_idx * 128, n0 = n_idx * 128;
    const int lrow = lane >> 3;
    const int gu = (lane & 7) ^ lrow;

    floatx4 acc[4][4];
#pragma unroll
    for (int i = 0; i < 4; ++i)
#pragma unroll
        for (int j = 0; j < 4; ++j) {
            floatx4 zz = {0.f, 0.f, 0.f, 0.f};
            acc[i][j] = zz;
        }

    uint4 p1[4], p2[4];
    float la_[4], lb_[4];

#define LOAD_AO(tt)                                                                \
    {                                                                              \
        _Pragma("unroll") for (int j = 0; j < 4; ++j) {                            \
            int c = wv * 4 + j;                                                    \
            int row = m0 + c * 8 + lrow;                                           \
            int col = (tt)*64 + gu * 8;                                            \
            p1[j] = *(const uint4*)(O1 + (size_t)row * E_ + col);                  \
            p2[j] = *(const uint4*)(O2 + (size_t)row * E_ + col);                  \
            int li = (row >> 11) * (H_ * L_) + (tt)*L_ + (row & (L_ - 1));         \
            la_[j] = l1[li];                                                       \
            lb_[j] = l2[li];                                                       \
        }                                                                          \
    }

#define WRITE_AO(buf)                                                              \
    {                                                                              \
        _Pragma("unroll") for (int j = 0; j < 4; ++j) {                            \
            int c = wv * 4 + j;                                                    \
            float s = 1.0f / (la_[j] + lb_[j]);                                    \
            float w1 = la_[j] * s, w2 = lb_[j] * s;                                \
            const u32* pa = (const u32*)&p1[j];                                    \
            const u32* pb = (const u32*)&p2[j];                                    \
            uint4 o;                                                               \
            u32* po = (u32*)&o;                                                    \
            _Pragma("unroll") for (int d = 0; d < 4; ++d) {                        \
                union { u32 u; float f; } x0, x1, y0, y1;                          \
                x0.u = pa[d] << 16; x1.u = pa[d] & 0xFFFF0000u;                    \
                y0.u = pb[d] << 16; y1.u = pb[d] & 0xFFFF0000u;                    \
                po[d] = cvt_pk_bf16(x0.f * w1 + y0.f * w2, x1.f * w1 + y1.f * w2); \
            }                                                                      \
            *(uint4*)(&As[buf][c * 512 + lane * 8]) = o;                           \
        }                                                                          \
    }

#define STAGE_BO(buf, kb)                                                          \
    {                                                                              \
        _Pragma("unroll") for (int j = 0; j < 4; ++j) {                            \
            int c = wv * 4 + j;                                                    \
            glds16(WpT + (size_t)(n0 + c * 8 + lrow) * E_ + (kb) + gu * 8,         \
                   &Bs[buf][c * 512]);                                             \
        }                                                                          \
    }

    LOAD_AO(0)
    STAGE_BO(0, 0)
    WRITE_AO(0)
    __syncthreads();

    for (int t = 0; t < 16; ++t) {
        const int cur = t & 1;
        if (t + 1 < 16) {
            STAGE_BO(cur ^ 1, (t + 1) * 64)
            LOAD_AO(t + 1)
        }

        short8 af[4][2], bf[4][2];
#pragma unroll
        for (int mi = 0; mi < 4; ++mi)
#pragma unroll
            for (int kk = 0; kk < 2; ++kk) {
                int row = wm * 64 + mi * 16 + lr;
                int u = (kk * 4 + qd) ^ (lr & 7);
                af[mi][kk] = *(const short8*)(&As[cur][row * 64 + u * 8]);
            }
#pragma unroll
        for (int ni = 0; ni < 4; ++ni)
#pragma unroll
            for (int kk = 0; kk < 2; ++kk) {
                int row = wn * 64 + ni * 16 + lr;
                int u = (kk * 4 + qd) ^ (lr & 7);
                bf[ni][kk] = *(const short8*)(&Bs[cur][row * 64 + u * 8]);
            }
        __builtin_amdgcn_s_setprio(1);
#pragma unroll
        for (int kk = 0; kk < 2; ++kk)
#pragma unroll
            for (int mi = 0; mi < 4; ++mi)
#pragma unroll
                for (int ni = 0; ni < 4; ++ni)
                    acc[mi][ni] = __builtin_amdgcn_mfma_f32_16x16x32_bf16(
                        af[mi][kk], bf[ni][kk], acc[mi][ni], 0, 0, 0);
        __builtin_amdgcn_s_setprio(0);

        if (t + 1 < 16) WRITE_AO(cur ^ 1)
        __syncthreads();
    }

#pragma unroll
    for (int mi = 0; mi < 4; ++mi)
#pragma unroll
        for (int ni = 0; ni < 4; ++ni) {
            int col = n0 + wn * 64 + ni * 16 + lr;
            float bv_ = bp[col];
#pragma unroll
            for (int r = 0; r < 4; ++r) {
                int row = m0 + wm * 64 + mi * 16 + qd * 4 + r;
                out[(size_t)row * E_ + col] = acc[mi][ni][r] + bv_;
            }
        }
#undef LOAD_AO
#undef WRITE_AO
#undef STAGE_BO
}

// ---------------------------------------------------------------------------
extern "C" void kernel_launch(void* const* d_in, const int* in_sizes, int n_in,
                              void* d_out, int out_size, void* d_ws, size_t ws_size,
                              hipStream_t stream) {
    const float* x   = (const float*)d_in[0];
    const float* ctx = (const float*)d_in[1];
    const float* Wq  = (const float*)d_in[2];
    const float* bq  = (const float*)d_in[3];
    const float* Wk  = (const float*)d_in[4];
    const float* bk  = (const float*)d_in[5];
    const float* Wv  = (const float*)d_in[6];
    const float* bv  = (const float*)d_in[7];
    const float* Wp  = (const float*)d_in[8];
    const float* bp  = (const float*)d_in[9];
    float* out = (float*)d_out;

    // workspace (u16 elems): WqT..WpT 4x1M | Qb 4M | Kb 4M | Vtb 4M |
    // Xb 4M | Cb 4M (Xb/Cb reused as Opart[0/1] after projections) | lpart
    u16* WqT = (u16*)d_ws;
    u16* WkT = WqT + 1048576;
    u16* WvT = WkT + 1048576;
    u16* WpT = WvT + 1048576;
    u16* Qb  = WpT + 1048576;
    u16* Kb  = Qb + 4194304;
    u16* Vtb = Kb + 4194304;
    u16* Xb  = Vtb + 4194304;
    u16* Cb  = Xb + 4194304;
    u16* Opart = Xb;  // overlays Xb/Cb (dead after projections)
    float* lpart = (float*)(Cb + 4194304);
    (void)ws_size; (void)in_sizes; (void)n_in; (void)out_size;

    cast_bf16_kernel<<<dim3(2048, 2), 256, 0, stream>>>(x, ctx, Xb, Cb);
    transpose_cast_kernel<<<dim3(32, 32, 4), dim3(32, 8), 0, stream>>>(
        Wq, Wk, Wv, Wp, WqT, WkT, WvT, WpT);

    qkv_gemm_kernel<<<dim3(8, 32, 3), 256, 0, stream>>>(
        Xb, Cb, WqT, WkT, WvT, bq, bk, bv, Qb, Kb, Vtb);

    flash_attn_kernel<<<dim3(L_ / 128, B_ * H_, 2), 256, 0, stream>>>(
        Qb, Kb, Vtb, Opart, lpart);

    out_gemm_kernel<<<dim3(8, 32), 256, 0, stream>>>(
        Opart, Opart + 4194304, lpart, lpart + B_ * H_ * L_, WpT, bp, out);
}

// Round 3
// 205.708 us; speedup vs baseline: 1.1651x; 1.0513x over previous
//
#include <hip/hip_runtime.h>
#include <math.h>

// Problem constants
#define B_ 2
#define L_ 2048
#define S_ 2048
#define E_ 1024
#define H_ 16
#define D_ 64
#define SC_ 0.180336880111120f  // (1/sqrt(64)) * log2(e), folded into Q projection

typedef unsigned short u16;
typedef unsigned int u32;
typedef __attribute__((ext_vector_type(8))) short short8;    // 8 bf16 (4 VGPRs)
typedef __attribute__((ext_vector_type(4))) float floatx4;   // 16x16 accum

__device__ __forceinline__ u16 f2bf(float f) {
    union { float f; unsigned u; } a; a.f = f;
    unsigned r = a.u + 0x7FFFu + ((a.u >> 16) & 1u);  // RNE
    return (u16)(r >> 16);
}

// pack two f32 -> bf16x2 (RNE), single instruction
__device__ __forceinline__ u32 cvt_pk_bf16(float lo, float hi) {
    u32 d;
    asm("v_cvt_pk_bf16_f32 %0, %1, %2" : "=v"(d) : "v"(lo), "v"(hi));
    return d;
}

// cross-lane half-swaps (gfx950): both operands are read-write.
// P32: a' = [a0,a1,b0,b1], b' = [a2,a3,b2,b3]   (rows = 16-lane groups)
// P16: a' = [a0,b0,a2,b2], b' = [a1,b1,a3,b3]
__device__ __forceinline__ void pl32swap(u32& a, u32& b) {
    asm("v_permlane32_swap_b32 %0, %1" : "+v"(a), "+v"(b));
}
__device__ __forceinline__ void pl16swap(u32& a, u32& b) {
    asm("v_permlane16_swap_b32 %0, %1" : "+v"(a), "+v"(b));
}

// async global->LDS, 16B per lane; LDS dest = wave-uniform base + lane*16
__device__ __forceinline__ void glds16(const u16* g, u16* l) {
    __builtin_amdgcn_global_load_lds(
        (const __attribute__((address_space(1))) void*)g,
        (__attribute__((address_space(3))) void*)l, 16, 0, 0);
}

// ---------------------------------------------------------------------------
// Merged prep kernel (saves one launch):
//   bid < 4096 : f32 -> bf16 cast of x (bid<2048) / ctx (bid>=2048)
//   bid >= 4096: weight transpose+cast, Wt[n][k] = bf16(W[k][n])
// ---------------------------------------------------------------------------
__global__ void prep_kernel(const float* __restrict__ x, const float* __restrict__ ctx,
                            u16* __restrict__ Xb, u16* __restrict__ Cb,
                            const float* __restrict__ Wq, const float* __restrict__ Wk,
                            const float* __restrict__ Wv, const float* __restrict__ Wp,
                            u16* __restrict__ WqT, u16* __restrict__ WkT,
                            u16* __restrict__ WvT, u16* __restrict__ WpT) {
    __shared__ float tile[32][33];
    const int bid = blockIdx.x;
    const int tid = threadIdx.x;
    if (bid < 4096) {
        const int sub = bid;
        const float* src = sub < 2048 ? x : ctx;
        u16* dst = sub < 2048 ? Xb : Cb;
        int i = (sub & 2047) * 256 + tid;
        float4 u0 = ((const float4*)src)[2 * i];
        float4 u1 = ((const float4*)src)[2 * i + 1];
        uint4 o;
        o.x = cvt_pk_bf16(u0.x, u0.y);
        o.y = cvt_pk_bf16(u0.z, u0.w);
        o.z = cvt_pk_bf16(u1.x, u1.y);
        o.w = cvt_pk_bf16(u1.z, u1.w);
        ((uint4*)dst)[i] = o;
    } else {
        const int t = bid - 4096;
        const int z = t >> 10;
        const int rem = t & 1023;
        const float* W = z == 0 ? Wq : (z == 1 ? Wk : (z == 2 ? Wv : Wp));
        u16* Wt = z == 0 ? WqT : (z == 1 ? WkT : (z == 2 ? WvT : WpT));
        const int bx = (rem & 31) * 32, by = (rem >> 5) * 32;
        const int tx = tid & 31, ty = tid >> 5;  // (32, 8)
#pragma unroll
        for (int j = 0; j < 4; ++j)
            tile[ty + j * 8][tx] = W[(size_t)(by + ty + j * 8) * E_ + bx + tx];
        __syncthreads();
#pragma unroll
        for (int j = 0; j < 4; ++j)
            Wt[(size_t)(bx + ty + j * 8) * E_ + by + tx] = f2bf(tile[tx][ty + j * 8]);
    }
}

// ---------------------------------------------------------------------------
// XCD-aware block remap for (8 n-tiles) x (32 m-tiles) grids.
// ---------------------------------------------------------------------------
__device__ __forceinline__ void xcd_remap(int bx, int by, int& m_idx, int& n_idx) {
    int lin = bx + 8 * by;       // 0..255
    int c8 = lin & 7;            // ~XCD
    int g = lin >> 3;            // 0..31
    m_idx = c8 + 8 * (g & 3);    // 0..31 ; m_idx % 8 == c8
    n_idx = g >> 2;              // 0..7
}

// ---------------------------------------------------------------------------
// Fused QKV projection GEMM (unchanged): BM=128 BN=128 BK=64, 256 threads,
// double-buffered glds16, XOR-swizzled LDS, XCD remap.
// ---------------------------------------------------------------------------
__global__ __launch_bounds__(256, 2) void qkv_gemm_kernel(
    const u16* __restrict__ Xb, const u16* __restrict__ Cb,
    const u16* __restrict__ WqT, const u16* __restrict__ WkT, const u16* __restrict__ WvT,
    const float* __restrict__ bq, const float* __restrict__ bk, const float* __restrict__ bv,
    u16* __restrict__ Qb, u16* __restrict__ Kb, u16* __restrict__ Vtb) {
    __shared__ __align__(16) u16 As[2][128 * 64];  // 2 x 16 KB
    __shared__ __align__(16) u16 Bs[2][128 * 64];  // 2 x 16 KB

    const int z = blockIdx.z;
    const u16* A  = z == 0 ? Xb : Cb;
    const u16* Bt = z == 0 ? WqT : (z == 1 ? WkT : WvT);
    const float* bias = z == 0 ? bq : (z == 1 ? bk : bv);
    const float scale = z == 0 ? SC_ : 1.0f;

    const int tid = threadIdx.x;
    const int lane = tid & 63;
    const int wv = tid >> 6;
    const int wm = wv >> 1, wn = wv & 1;
    const int qd = lane >> 4, lr = lane & 15;
    int m_idx, n_idx;
    xcd_remap(blockIdx.x, blockIdx.y, m_idx, n_idx);
    const int m0 = m_idx * 128, n0 = n_idx * 128;
    const int lrow = lane >> 3;        // 0..7
    const int gu = (lane & 7) ^ lrow;  // swizzled global 16B-unit

    floatx4 acc[4][4];
#pragma unroll
    for (int i = 0; i < 4; ++i)
#pragma unroll
        for (int j = 0; j < 4; ++j) {
            floatx4 zz = {0.f, 0.f, 0.f, 0.f};
            acc[i][j] = zz;
        }

#define STAGE_AB(buf, kb)                                                          \
    {                                                                              \
        _Pragma("unroll") for (int j = 0; j < 4; ++j) {                            \
            int c = wv * 4 + j;                                                    \
            glds16(A + (size_t)(m0 + c * 8 + lrow) * E_ + (kb) + gu * 8,           \
                   &As[buf][c * 512]);                                             \
            glds16(Bt + (size_t)(n0 + c * 8 + lrow) * E_ + (kb) + gu * 8,          \
                   &Bs[buf][c * 512]);                                             \
        }                                                                          \
    }

    STAGE_AB(0, 0)
    __syncthreads();  // tile 0 landed (vmcnt drained at barrier)

    for (int t = 0; t < 16; ++t) {
        const int cur = t & 1;
        if (t + 1 < 16) STAGE_AB(cur ^ 1, (t + 1) * 64)

        short8 af[4][2], bf[4][2];
#pragma unroll
        for (int mi = 0; mi < 4; ++mi)
#pragma unroll
            for (int kk = 0; kk < 2; ++kk) {
                int row = wm * 64 + mi * 16 + lr;
                int u = (kk * 4 + qd) ^ (lr & 7);
                af[mi][kk] = *(const short8*)(&As[cur][row * 64 + u * 8]);
            }
#pragma unroll
        for (int ni = 0; ni < 4; ++ni)
#pragma unroll
            for (int kk = 0; kk < 2; ++kk) {
                int row = wn * 64 + ni * 16 + lr;
                int u = (kk * 4 + qd) ^ (lr & 7);
                bf[ni][kk] = *(const short8*)(&Bs[cur][row * 64 + u * 8]);
            }
        __builtin_amdgcn_s_setprio(1);
#pragma unroll
        for (int kk = 0; kk < 2; ++kk)
#pragma unroll
            for (int mi = 0; mi < 4; ++mi)
#pragma unroll
                for (int ni = 0; ni < 4; ++ni)
                    acc[mi][ni] = __builtin_amdgcn_mfma_f32_16x16x32_bf16(
                        af[mi][kk], bf[ni][kk], acc[mi][ni], 0, 0, 0);
        __builtin_amdgcn_s_setprio(0);

        __syncthreads();  // readers done with cur; prefetch into cur^1 drained
    }

    // epilogue: C/D row = qd*4+r, col = lane&15
    u16* Cq = z == 0 ? Qb : Kb;
#pragma unroll
    for (int mi = 0; mi < 4; ++mi) {
#pragma unroll
        for (int ni = 0; ni < 4; ++ni) {
            int col = n0 + wn * 64 + ni * 16 + lr;
            float bv_ = bias[col];
            if (z == 2) {
                int row0 = m0 + wm * 64 + mi * 16 + qd * 4;
                int bidx = row0 >> 11;
                int sloc = row0 & (S_ - 1);
                u16 h0 = f2bf(acc[mi][ni][0] + bv_);
                u16 h1 = f2bf(acc[mi][ni][1] + bv_);
                u16 h2 = f2bf(acc[mi][ni][2] + bv_);
                u16 h3 = f2bf(acc[mi][ni][3] + bv_);
                uint2 pk;
                pk.x = h0 | ((unsigned)h1 << 16);
                pk.y = h2 | ((unsigned)h3 << 16);
                *(uint2*)&Vtb[((size_t)(bidx * E_ + col)) * S_ + sloc] = pk;
            } else {
#pragma unroll
                for (int r = 0; r < 4; ++r) {
                    int row = m0 + wm * 64 + mi * 16 + qd * 4 + r;
                    Cq[(size_t)row * E_ + col] = f2bf((acc[mi][ni][r] + bv_) * scale);
                }
            }
        }
    }
#undef STAGE_AB
}

// ---------------------------------------------------------------------------
// Flash attention, in-register softmax + XCD-group remap + MFMA l-sum:
// grid (L/128, B*H, 2), 256 threads (4 waves). l[q] is computed by an extra
// PV-style MFMA against a constant ones-vector B-operand (every output col
// = row-sum of P), eliminating the ~26 VALU adds/iter and the epilogue
// shuffle reduction. l thus sums the SAME bf16-rounded P used in PV.
// ---------------------------------------------------------------------------
__global__ __launch_bounds__(256, 4) void flash_attn_kernel(
    const u16* __restrict__ Q, const u16* __restrict__ Kg,
    const u16* __restrict__ Vtg, u16* __restrict__ Opart, float* __restrict__ lpart) {
    __shared__ __align__(16) u16 Ks[2][64 * 64];  // 2 x 8 KB (swizzled)
    __shared__ __align__(16) u16 Vs[2][64 * 64];  // 2 x 8 KB, V^T layout [d][s]

    const int tid = threadIdx.x;
    const int lane = tid & 63;
    const int wv = tid >> 6;
    const int qd = lane >> 4, lr = lane & 15;

    // XCD-group remap: all 16 q-tiles of one (b,h,z) on the same XCD.
    const int lin = blockIdx.x + 16 * (blockIdx.y + 32 * blockIdx.z);
    const int c8 = lin & 7;
    const int slot = lin >> 3;            // 0..127
    const int qx = slot & 15;             // q-tile index
    const int grp = c8 + 8 * (slot >> 4); // 0..63 = (bh, z)
    const int bh = grp & 31;
    const int z = grp >> 5;
    const int b = bh >> 4, h = bh & 15;
    const int q0 = qx * 128;
    const int sbeg = z * (S_ / 2);

    u16* Op = Opart + (size_t)z * (B_ * L_ * E_);
    float* lp = lpart + (size_t)z * (B_ * H_ * L_);

    const u16* Kbase = Kg + (size_t)(b * S_) * E_ + h * D_;
    const u16* Vbase = Vtg + (size_t)(b * E_ + h * D_) * S_;  // rows=d, cols=s

    const int lrow = lane >> 3;        // 0..7
    const int gu = (lane & 7) ^ lrow;  // swizzled global 16B-unit

    // issue K/V tile 0 loads first (in flight during Q fragment loads)
#pragma unroll
    for (int j = 0; j < 2; ++j) {
        int c = wv * 2 + j;
        glds16(Kbase + (size_t)(sbeg + c * 8 + lrow) * E_ + gu * 8, &Ks[0][c * 512]);
        glds16(Vbase + (size_t)(c * 8 + lrow) * S_ + sbeg + gu * 8, &Vs[0][c * 512]);
    }

    // Q fragments (B-operand: col=q=lr, k=d=kk*32+qd*8..+7) direct from global.
    short8 qf[2][2];
#pragma unroll
    for (int mi = 0; mi < 2; ++mi)
#pragma unroll
        for (int kk = 0; kk < 2; ++kk)
            qf[mi][kk] = *(const short8*)(Q + (size_t)(b * L_ + q0 + wv * 32 + mi * 16 + lr) * E_ +
                                          h * D_ + kk * 32 + qd * 8);

    // constant ones B-operand (bf16 1.0 = 0x3F80) for the l-sum MFMA
    const short one_bf = (short)0x3F80;
    short8 ones8 = {one_bf, one_bf, one_bf, one_bf, one_bf, one_bf, one_bf, one_bf};

    floatx4 o_acc[2][4];
    floatx4 l4[2];
#pragma unroll
    for (int mi = 0; mi < 2; ++mi) {
#pragma unroll
        for (int nt = 0; nt < 4; ++nt) {
            floatx4 z4 = {0.f, 0.f, 0.f, 0.f};
            o_acc[mi][nt] = z4;
        }
        floatx4 z4 = {0.f, 0.f, 0.f, 0.f};
        l4[mi] = z4;
    }

    __syncthreads();  // K/V tile 0 landed

    const int NIT = (S_ / 2) / 64;  // 16

    for (int it = 0; it < NIT; ++it) {
        const int cur = it & 1;
        // prefetch next K/V tile into the other buffer (in flight during compute)
        if (it + 1 < NIT) {
            int s1 = sbeg + (it + 1) * 64;
#pragma unroll
            for (int j = 0; j < 2; ++j) {
                int c = wv * 2 + j;
                glds16(Kbase + (size_t)(s1 + c * 8 + lrow) * E_ + gu * 8, &Ks[cur ^ 1][c * 512]);
                glds16(Vbase + (size_t)(c * 8 + lrow) * S_ + s1 + gu * 8, &Vs[cur ^ 1][c * 512]);
            }
        }

        // ---- S'^T = K Q^T (swapped): D[s][q], lane holds q=lr, s=nt*16+qd*4+r ----
        floatx4 s_[2][4];
        __builtin_amdgcn_s_setprio(1);
#pragma unroll
        for (int nt = 0; nt < 4; ++nt) {
            int krow = nt * 16 + lr;
            short8 kb0 = *(const short8*)(&Ks[cur][krow * 64 + ((qd) ^ (lr & 7)) * 8]);
            short8 kb1 = *(const short8*)(&Ks[cur][krow * 64 + ((4 + qd) ^ (lr & 7)) * 8]);
#pragma unroll
            for (int mi = 0; mi < 2; ++mi) {
                floatx4 zz = {0.f, 0.f, 0.f, 0.f};
                zz = __builtin_amdgcn_mfma_f32_16x16x32_bf16(kb0, qf[mi][0], zz, 0, 0, 0);
                zz = __builtin_amdgcn_mfma_f32_16x16x32_bf16(kb1, qf[mi][1], zz, 0, 0, 0);
                s_[mi][nt] = zz;
            }
        }
        __builtin_amdgcn_s_setprio(0);

        // ---- p = exp2(s'); pack bf16 pairs; permlane exchange -> PV A-frags ----
        short8 pf[2][2];
#pragma unroll
        for (int mi = 0; mi < 2; ++mi) {
            u32 dg[4][2];
#pragma unroll
            for (int nt = 0; nt < 4; ++nt) {
                float p0 = __builtin_amdgcn_exp2f(s_[mi][nt][0]);
                float p1 = __builtin_amdgcn_exp2f(s_[mi][nt][1]);
                float p2 = __builtin_amdgcn_exp2f(s_[mi][nt][2]);
                float p3 = __builtin_amdgcn_exp2f(s_[mi][nt][3]);
                dg[nt][0] = cvt_pk_bf16(p0, p1);
                dg[nt][1] = cvt_pk_bf16(p2, p3);
            }
#pragma unroll
            for (int kk = 0; kk < 2; ++kk) {
                u32 x0 = dg[2 * kk][0], y0 = dg[2 * kk + 1][0];
                pl32swap(x0, y0);  // x0=[X0,X1,Y0,Y1] y0=[X2,X3,Y2,Y3]
                pl16swap(x0, y0);  // x0=[X0,X2,Y0,Y2] y0=[X1,X3,Y1,Y3]
                u32 x1 = dg[2 * kk][1], y1 = dg[2 * kk + 1][1];
                pl32swap(x1, y1);
                pl16swap(x1, y1);
                union { u32 d[4]; short8 v; } u;
                u.d[0] = x0; u.d[1] = x1; u.d[2] = y0; u.d[3] = y1;
                pf[mi][kk] = u.v;
            }
        }

        // ---- O += P V ; l += P * ones (row-sum via MFMA) ----
        __builtin_amdgcn_s_setprio(1);
#pragma unroll
        for (int mi = 0; mi < 2; ++mi) {
            l4[mi] = __builtin_amdgcn_mfma_f32_16x16x32_bf16(pf[mi][0], ones8, l4[mi], 0, 0, 0);
            l4[mi] = __builtin_amdgcn_mfma_f32_16x16x32_bf16(pf[mi][1], ones8, l4[mi], 0, 0, 0);
        }
#pragma unroll
        for (int nt = 0; nt < 4; ++nt) {
            int vrow = nt * 16 + lr;
            short8 vb0 = *(const short8*)(&Vs[cur][vrow * 64 + ((qd) ^ (lr & 7)) * 8]);
            short8 vb1 = *(const short8*)(&Vs[cur][vrow * 64 + ((4 + qd) ^ (lr & 7)) * 8]);
#pragma unroll
            for (int mi = 0; mi < 2; ++mi) {
                o_acc[mi][nt] = __builtin_amdgcn_mfma_f32_16x16x32_bf16(pf[mi][0], vb0, o_acc[mi][nt], 0, 0, 0);
                o_acc[mi][nt] = __builtin_amdgcn_mfma_f32_16x16x32_bf16(pf[mi][1], vb1, o_acc[mi][nt], 0, 0, 0);
            }
        }
        __builtin_amdgcn_s_setprio(0);

        __syncthreads();  // readers done with cur; prefetch into cur^1 drained
    }

    // ---- epilogue: l4[mi][r] = l for row qd*4+r (all lanes); no shuffles ----
    float linv[2][4];
#pragma unroll
    for (int mi = 0; mi < 2; ++mi) {
        if (lr == 0) {
#pragma unroll
            for (int r = 0; r < 4; ++r)
                lp[(size_t)(b * H_ + h) * L_ + q0 + wv * 32 + mi * 16 + qd * 4 + r] = l4[mi][r];
        }
#pragma unroll
        for (int r = 0; r < 4; ++r) linv[mi][r] = 1.0f / l4[mi][r];
    }

#pragma unroll
    for (int mi = 0; mi < 2; ++mi)
#pragma unroll
        for (int nt = 0; nt < 4; ++nt)
#pragma unroll
            for (int r = 0; r < 4; ++r) {
                int row = q0 + wv * 32 + mi * 16 + qd * 4 + r;
                int col = h * D_ + nt * 16 + lr;
                Op[(size_t)(b * L_ + row) * E_ + col] = f2bf(o_acc[mi][nt][r] * linv[mi][r]);
            }
}

// ---------------------------------------------------------------------------
// Output GEMM with fused split-S combine. BM=64 BN=128 BK=64 -> grid (8,64)
// = 512 blocks = 2 blocks/CU (was 1 block/CU at BM=128 — latency-starved).
// LDS 48 KB. Wave tile 32x64 (acc[2][4]).
// ---------------------------------------------------------------------------
__global__ __launch_bounds__(256, 2) void out_gemm_kernel(
    const u16* __restrict__ O1, const u16* __restrict__ O2,
    const float* __restrict__ l1, const float* __restrict__ l2,
    const u16* __restrict__ WpT, const float* __restrict__ bp,
    float* __restrict__ out) {
    __shared__ __align__(16) u16 As[2][64 * 64];   // 2 x 8 KB
    __shared__ __align__(16) u16 Bs[2][128 * 64];  // 2 x 16 KB

    const int tid = threadIdx.x;
    const int lane = tid & 63;
    const int wv = tid >> 6;
    const int wm = wv >> 1, wn = wv & 1;
    const int qd = lane >> 4, lr = lane & 15;

    // XCD remap for (8 n) x (64 m): m_idx % 8 == XCD slot
    int lin = blockIdx.x + 8 * blockIdx.y;  // 0..511
    int c8 = lin & 7;
    int g = lin >> 3;                        // 0..63
    const int m_idx = c8 + 8 * (g & 7);      // 0..63
    const int n_idx = g >> 3;                // 0..7
    const int m0 = m_idx * 64, n0 = n_idx * 128;
    const int lrow = lane >> 3;
    const int gu = (lane & 7) ^ lrow;

    floatx4 acc[2][4];
#pragma unroll
    for (int i = 0; i < 2; ++i)
#pragma unroll
        for (int j = 0; j < 4; ++j) {
            floatx4 zz = {0.f, 0.f, 0.f, 0.f};
            acc[i][j] = zz;
        }

    uint4 p1[2], p2[2];
    float la_[2], lb_[2];

#define LOAD_AO(tt)                                                                \
    {                                                                              \
        _Pragma("unroll") for (int j = 0; j < 2; ++j) {                            \
            int c = wv * 2 + j;                                                    \
            int row = m0 + c * 8 + lrow;                                           \
            int col = (tt)*64 + gu * 8;                                            \
            p1[j] = *(const uint4*)(O1 + (size_t)row * E_ + col);                  \
            p2[j] = *(const uint4*)(O2 + (size_t)row * E_ + col);                  \
            int li = (row >> 11) * (H_ * L_) + (tt)*L_ + (row & (L_ - 1));         \
            la_[j] = l1[li];                                                       \
            lb_[j] = l2[li];                                                       \
        }                                                                          \
    }

#define WRITE_AO(buf)                                                              \
    {                                                                              \
        _Pragma("unroll") for (int j = 0; j < 2; ++j) {                            \
            int c = wv * 2 + j;                                                    \
            float s = 1.0f / (la_[j] + lb_[j]);                                    \
            float w1 = la_[j] * s, w2 = lb_[j] * s;                                \
            const u32* pa = (const u32*)&p1[j];                                    \
            const u32* pb = (const u32*)&p2[j];                                    \
            uint4 o;                                                               \
            u32* po = (u32*)&o;                                                    \
            _Pragma("unroll") for (int d = 0; d < 4; ++d) {                        \
                union { u32 u; float f; } x0, x1, y0, y1;                          \
                x0.u = pa[d] << 16; x1.u = pa[d] & 0xFFFF0000u;                    \
                y0.u = pb[d] << 16; y1.u = pb[d] & 0xFFFF0000u;                    \
                po[d] = cvt_pk_bf16(x0.f * w1 + y0.f * w2, x1.f * w1 + y1.f * w2); \
            }                                                                      \
            *(uint4*)(&As[buf][c * 512 + lane * 8]) = o;                           \
        }                                                                          \
    }

#define STAGE_BO(buf, kb)                                                          \
    {                                                                              \
        _Pragma("unroll") for (int j = 0; j < 4; ++j) {                            \
            int c = wv * 4 + j;                                                    \
            glds16(WpT + (size_t)(n0 + c * 8 + lrow) * E_ + (kb) + gu * 8,         \
                   &Bs[buf][c * 512]);                                             \
        }                                                                          \
    }

    LOAD_AO(0)
    STAGE_BO(0, 0)
    WRITE_AO(0)
    __syncthreads();

    for (int t = 0; t < 16; ++t) {
        const int cur = t & 1;
        if (t + 1 < 16) {
            STAGE_BO(cur ^ 1, (t + 1) * 64)
            LOAD_AO(t + 1)
        }

        short8 af[2][2], bf[4][2];
#pragma unroll
        for (int mi = 0; mi < 2; ++mi)
#pragma unroll
            for (int kk = 0; kk < 2; ++kk) {
                int row = wm * 32 + mi * 16 + lr;
                int u = (kk * 4 + qd) ^ (lr & 7);
                af[mi][kk] = *(const short8*)(&As[cur][row * 64 + u * 8]);
            }
#pragma unroll
        for (int ni = 0; ni < 4; ++ni)
#pragma unroll
            for (int kk = 0; kk < 2; ++kk) {
                int row = wn * 64 + ni * 16 + lr;
                int u = (kk * 4 + qd) ^ (lr & 7);
                bf[ni][kk] = *(const short8*)(&Bs[cur][row * 64 + u * 8]);
            }
        __builtin_amdgcn_s_setprio(1);
#pragma unroll
        for (int kk = 0; kk < 2; ++kk)
#pragma unroll
            for (int mi = 0; mi < 2; ++mi)
#pragma unroll
                for (int ni = 0; ni < 4; ++ni)
                    acc[mi][ni] = __builtin_amdgcn_mfma_f32_16x16x32_bf16(
                        af[mi][kk], bf[ni][kk], acc[mi][ni], 0, 0, 0);
        __builtin_amdgcn_s_setprio(0);

        if (t + 1 < 16) WRITE_AO(cur ^ 1)
        __syncthreads();
    }

#pragma unroll
    for (int mi = 0; mi < 2; ++mi)
#pragma unroll
        for (int ni = 0; ni < 4; ++ni) {
            int col = n0 + wn * 64 + ni * 16 + lr;
            float bv_ = bp[col];
#pragma unroll
            for (int r = 0; r < 4; ++r) {
                int row = m0 + wm * 32 + mi * 16 + qd * 4 + r;
                out[(size_t)row * E_ + col] = acc[mi][ni][r] + bv_;
            }
        }
#undef LOAD_AO
#undef WRITE_AO
#undef STAGE_BO
}

// ---------------------------------------------------------------------------
extern "C" void kernel_launch(void* const* d_in, const int* in_sizes, int n_in,
                              void* d_out, int out_size, void* d_ws, size_t ws_size,
                              hipStream_t stream) {
    const float* x   = (const float*)d_in[0];
    const float* ctx = (const float*)d_in[1];
    const float* Wq  = (const float*)d_in[2];
    const float* bq  = (const float*)d_in[3];
    const float* Wk  = (const float*)d_in[4];
    const float* bk  = (const float*)d_in[5];
    const float* Wv  = (const float*)d_in[6];
    const float* bv  = (const float*)d_in[7];
    const float* Wp  = (const float*)d_in[8];
    const float* bp  = (const float*)d_in[9];
    float* out = (float*)d_out;

    // workspace (u16 elems): WqT..WpT 4x1M | Qb 4M | Kb 4M | Vtb 4M |
    // Xb 4M | Cb 4M (Xb/Cb reused as Opart[0/1] after projections) | lpart
    u16* WqT = (u16*)d_ws;
    u16* WkT = WqT + 1048576;
    u16* WvT = WkT + 1048576;
    u16* WpT = WvT + 1048576;
    u16* Qb  = WpT + 1048576;
    u16* Kb  = Qb + 4194304;
    u16* Vtb = Kb + 4194304;
    u16* Xb  = Vtb + 4194304;
    u16* Cb  = Xb + 4194304;
    u16* Opart = Xb;  // overlays Xb/Cb (dead after projections)
    float* lpart = (float*)(Cb + 4194304);
    (void)ws_size; (void)in_sizes; (void)n_in; (void)out_size;

    prep_kernel<<<dim3(8192), 256, 0, stream>>>(
        x, ctx, Xb, Cb, Wq, Wk, Wv, Wp, WqT, WkT, WvT, WpT);

    qkv_gemm_kernel<<<dim3(8, 32, 3), 256, 0, stream>>>(
        Xb, Cb, WqT, WkT, WvT, bq, bk, bv, Qb, Kb, Vtb);

    flash_attn_kernel<<<dim3(L_ / 128, B_ * H_, 2), 256, 0, stream>>>(
        Qb, Kb, Vtb, Opart, lpart);

    out_gemm_kernel<<<dim3(8, 64), 256, 0, stream>>>(
        Opart, Opart + 4194304, lpart, lpart + B_ * H_ * L_, WpT, bp, out);
}

// Round 5
// 196.046 us; speedup vs baseline: 1.2225x; 1.0493x over previous
//
#include <hip/hip_runtime.h>
#include <math.h>

// Problem constants
#define B_ 2
#define L_ 2048
#define S_ 2048
#define E_ 1024
#define H_ 16
#define D_ 64
#define SC_ 0.180336880111120f  // (1/sqrt(64)) * log2(e), folded into Q projection

typedef unsigned short u16;
typedef unsigned int u32;
typedef __attribute__((ext_vector_type(8))) short short8;    // 8 bf16 (4 VGPRs)
typedef __attribute__((ext_vector_type(4))) float floatx4;   // 16x16 accum

__device__ __forceinline__ u16 f2bf(float f) {
    union { float f; unsigned u; } a; a.f = f;
    unsigned r = a.u + 0x7FFFu + ((a.u >> 16) & 1u);  // RNE
    return (u16)(r >> 16);
}

// pack two f32 -> bf16x2 (RNE), single instruction
__device__ __forceinline__ u32 cvt_pk_bf16(float lo, float hi) {
    u32 d;
    asm("v_cvt_pk_bf16_f32 %0, %1, %2" : "=v"(d) : "v"(lo), "v"(hi));
    return d;
}

// cross-lane half-swaps (gfx950): both operands are read-write.
// P32: a' = [a0,a1,b0,b1], b' = [a2,a3,b2,b3]   (rows = 16-lane groups)
// P16: a' = [a0,b0,a2,b2], b' = [a1,b1,a3,b3]
__device__ __forceinline__ void pl32swap(u32& a, u32& b) {
    asm("v_permlane32_swap_b32 %0, %1" : "+v"(a), "+v"(b));
}
__device__ __forceinline__ void pl16swap(u32& a, u32& b) {
    asm("v_permlane16_swap_b32 %0, %1" : "+v"(a), "+v"(b));
}

// async global->LDS, 16B per lane; LDS dest = wave-uniform base + lane*16
__device__ __forceinline__ void glds16(const u16* g, u16* l) {
    __builtin_amdgcn_global_load_lds(
        (const __attribute__((address_space(1))) void*)g,
        (__attribute__((address_space(3))) void*)l, 16, 0, 0);
}

// ---------------------------------------------------------------------------
// Merged prep kernel:
//   bid < 4096 : f32 -> bf16 cast of x (bid<2048) / ctx (bid>=2048)
//   bid >= 4096: weight transpose+cast, Wt[n][k] = bf16(W[k][n])
// ---------------------------------------------------------------------------
__global__ void prep_kernel(const float* __restrict__ x, const float* __restrict__ ctx,
                            u16* __restrict__ Xb, u16* __restrict__ Cb,
                            const float* __restrict__ Wq, const float* __restrict__ Wk,
                            const float* __restrict__ Wv, const float* __restrict__ Wp,
                            u16* __restrict__ WqT, u16* __restrict__ WkT,
                            u16* __restrict__ WvT, u16* __restrict__ WpT) {
    __shared__ float tile[32][33];
    const int bid = blockIdx.x;
    const int tid = threadIdx.x;
    if (bid < 4096) {
        const int sub = bid;
        const float* src = sub < 2048 ? x : ctx;
        u16* dst = sub < 2048 ? Xb : Cb;
        int i = (sub & 2047) * 256 + tid;
        float4 u0 = ((const float4*)src)[2 * i];
        float4 u1 = ((const float4*)src)[2 * i + 1];
        uint4 o;
        o.x = cvt_pk_bf16(u0.x, u0.y);
        o.y = cvt_pk_bf16(u0.z, u0.w);
        o.z = cvt_pk_bf16(u1.x, u1.y);
        o.w = cvt_pk_bf16(u1.z, u1.w);
        ((uint4*)dst)[i] = o;
    } else {
        const int t = bid - 4096;
        const int z = t >> 10;
        const int rem = t & 1023;
        const float* W = z == 0 ? Wq : (z == 1 ? Wk : (z == 2 ? Wv : Wp));
        u16* Wt = z == 0 ? WqT : (z == 1 ? WkT : (z == 2 ? WvT : WpT));
        const int bx = (rem & 31) * 32, by = (rem >> 5) * 32;
        const int tx = tid & 31, ty = tid >> 5;  // (32, 8)
#pragma unroll
        for (int j = 0; j < 4; ++j)
            tile[ty + j * 8][tx] = W[(size_t)(by + ty + j * 8) * E_ + bx + tx];
        __syncthreads();
#pragma unroll
        for (int j = 0; j < 4; ++j)
            Wt[(size_t)(bx + ty + j * 8) * E_ + by + tx] = f2bf(tile[tx][ty + j * 8]);
    }
}

// ---------------------------------------------------------------------------
// XCD-aware block remap for (8 n-tiles) x (32 m-tiles) grids.
// ---------------------------------------------------------------------------
__device__ __forceinline__ void xcd_remap(int bx, int by, int& m_idx, int& n_idx) {
    int lin = bx + 8 * by;       // 0..255
    int c8 = lin & 7;            // ~XCD
    int g = lin >> 3;            // 0..31
    m_idx = c8 + 8 * (g & 3);    // 0..31 ; m_idx % 8 == c8
    n_idx = g >> 2;              // 0..7
}

// ---------------------------------------------------------------------------
// Fused QKV projection GEMM: BM=128 BN=128 BK=64, 256 threads, double-
// buffered glds16, XOR-swizzled LDS, XCD remap. NEW: z==2 (V) epilogue
// transposes the C-tile through LDS (As/Bs dead after the K-loop; single
// unioned sm[] buffer) and writes Vtb with coalesced 16B stores along s —
// replaces the 8B-at-4KB-stride scatter (~8x HBM write amplification).
// ---------------------------------------------------------------------------
__global__ __launch_bounds__(256, 2) void qkv_gemm_kernel(
    const u16* __restrict__ Xb, const u16* __restrict__ Cb,
    const u16* __restrict__ WqT, const u16* __restrict__ WkT, const u16* __restrict__ WvT,
    const float* __restrict__ bq, const float* __restrict__ bk, const float* __restrict__ bv,
    u16* __restrict__ Qb, u16* __restrict__ Kb, u16* __restrict__ Vtb) {
    // sm layout (u16): [0,8192) As buf0 | [8192,16384) As buf1 |
    //                  [16384,24576) Bs buf0 | [24576,32768) Bs buf1
    // epilogue (z==2): [0, 128*136) C^T tile (d-major, stride 136)
    __shared__ __align__(16) u16 sm[32768];  // 64 KB

    const int z = blockIdx.z;
    const u16* A  = z == 0 ? Xb : Cb;
    const u16* Bt = z == 0 ? WqT : (z == 1 ? WkT : WvT);
    const float* bias = z == 0 ? bq : (z == 1 ? bk : bv);
    const float scale = z == 0 ? SC_ : 1.0f;

    const int tid = threadIdx.x;
    const int lane = tid & 63;
    const int wv = tid >> 6;
    const int wm = wv >> 1, wn = wv & 1;
    const int qd = lane >> 4, lr = lane & 15;
    int m_idx, n_idx;
    xcd_remap(blockIdx.x, blockIdx.y, m_idx, n_idx);
    const int m0 = m_idx * 128, n0 = n_idx * 128;
    const int lrow = lane >> 3;        // 0..7
    const int gu = (lane & 7) ^ lrow;  // swizzled global 16B-unit

    floatx4 acc[4][4];
#pragma unroll
    for (int i = 0; i < 4; ++i)
#pragma unroll
        for (int j = 0; j < 4; ++j) {
            floatx4 zz = {0.f, 0.f, 0.f, 0.f};
            acc[i][j] = zz;
        }

#define STAGE_AB(buf, kb)                                                          \
    {                                                                              \
        _Pragma("unroll") for (int j = 0; j < 4; ++j) {                            \
            int c = wv * 4 + j;                                                    \
            glds16(A + (size_t)(m0 + c * 8 + lrow) * E_ + (kb) + gu * 8,           \
                   sm + (buf)*8192 + c * 512);                                     \
            glds16(Bt + (size_t)(n0 + c * 8 + lrow) * E_ + (kb) + gu * 8,          \
                   sm + 16384 + (buf)*8192 + c * 512);                             \
        }                                                                          \
    }

    STAGE_AB(0, 0)
    __syncthreads();  // tile 0 landed (vmcnt drained at barrier)

    for (int t = 0; t < 16; ++t) {
        const int cur = t & 1;
        if (t + 1 < 16) STAGE_AB(cur ^ 1, (t + 1) * 64)

        short8 af[4][2], bf[4][2];
#pragma unroll
        for (int mi = 0; mi < 4; ++mi)
#pragma unroll
            for (int kk = 0; kk < 2; ++kk) {
                int row = wm * 64 + mi * 16 + lr;
                int u = (kk * 4 + qd) ^ (lr & 7);
                af[mi][kk] = *(const short8*)(sm + cur * 8192 + row * 64 + u * 8);
            }
#pragma unroll
        for (int ni = 0; ni < 4; ++ni)
#pragma unroll
            for (int kk = 0; kk < 2; ++kk) {
                int row = wn * 64 + ni * 16 + lr;
                int u = (kk * 4 + qd) ^ (lr & 7);
                bf[ni][kk] = *(const short8*)(sm + 16384 + cur * 8192 + row * 64 + u * 8);
            }
        __builtin_amdgcn_s_setprio(1);
#pragma unroll
        for (int kk = 0; kk < 2; ++kk)
#pragma unroll
            for (int mi = 0; mi < 4; ++mi)
#pragma unroll
                for (int ni = 0; ni < 4; ++ni)
                    acc[mi][ni] = __builtin_amdgcn_mfma_f32_16x16x32_bf16(
                        af[mi][kk], bf[ni][kk], acc[mi][ni], 0, 0, 0);
        __builtin_amdgcn_s_setprio(0);

        __syncthreads();  // readers done with cur; prefetch into cur^1 drained
    }

    // epilogue: C/D row = qd*4+r, col = lane&15
    if (z == 2) {
        // --- V: transpose C-tile (128 s-rows x 128 d-cols) via LDS, then
        //     coalesced global writes along s. LDS staging is dead here. ---
        const int CTS = 136;  // u16 stride: 272 B -> 8B/16B alignment holds
#pragma unroll
        for (int mi = 0; mi < 4; ++mi)
#pragma unroll
            for (int ni = 0; ni < 4; ++ni) {
                int col = wn * 64 + ni * 16 + lr;      // d within tile
                int row = wm * 64 + mi * 16 + qd * 4;  // s within tile
                float bv_ = bias[n0 + col];
                u16 h0 = f2bf(acc[mi][ni][0] + bv_);
                u16 h1 = f2bf(acc[mi][ni][1] + bv_);
                u16 h2 = f2bf(acc[mi][ni][2] + bv_);
                u16 h3 = f2bf(acc[mi][ni][3] + bv_);
                uint2 pk;
                pk.x = h0 | ((u32)h1 << 16);
                pk.y = h2 | ((u32)h3 << 16);
                *(uint2*)&sm[col * CTS + row] = pk;  // Ct[d][s], rows contiguous in s
            }
        __syncthreads();
        const int d = tid >> 1;          // 0..127
        const int sh = (tid & 1) * 64;   // s-half within tile
        const int bidx = m0 >> 11;
        const int sloc = m0 & (S_ - 1);
        u16* dstV = Vtb + ((size_t)(bidx * E_ + n0 + d)) * S_ + sloc + sh;
        const u16* srcC = sm + d * CTS + sh;
#pragma unroll
        for (int j = 0; j < 8; ++j)
            *(uint4*)(dstV + j * 8) = *(const uint4*)(srcC + j * 8);
    } else {
        u16* Cq = z == 0 ? Qb : Kb;
#pragma unroll
        for (int mi = 0; mi < 4; ++mi) {
#pragma unroll
            for (int ni = 0; ni < 4; ++ni) {
                int col = n0 + wn * 64 + ni * 16 + lr;
                float bv_ = bias[col];
#pragma unroll
                for (int r = 0; r < 4; ++r) {
                    int row = m0 + wm * 64 + mi * 16 + qd * 4 + r;
                    Cq[(size_t)row * E_ + col] = f2bf((acc[mi][ni][r] + bv_) * scale);
                }
            }
        }
    }
#undef STAGE_AB
}

// ---------------------------------------------------------------------------
// Flash attention (REVERTED to the r3-verified QBLK=32 structure):
// in-register softmax + XCD-group remap + MFMA l-sum.
// grid (L/128, B*H, 2), 256 threads (4 waves).
// ---------------------------------------------------------------------------
__global__ __launch_bounds__(256, 4) void flash_attn_kernel(
    const u16* __restrict__ Q, const u16* __restrict__ Kg,
    const u16* __restrict__ Vtg, u16* __restrict__ Opart, float* __restrict__ lpart) {
    __shared__ __align__(16) u16 Ks[2][64 * 64];  // 2 x 8 KB (swizzled)
    __shared__ __align__(16) u16 Vs[2][64 * 64];  // 2 x 8 KB, V^T layout [d][s]

    const int tid = threadIdx.x;
    const int lane = tid & 63;
    const int wv = tid >> 6;
    const int qd = lane >> 4, lr = lane & 15;

    // XCD-group remap: all 16 q-tiles of one (b,h,z) on the same XCD.
    const int lin = blockIdx.x + 16 * (blockIdx.y + 32 * blockIdx.z);
    const int c8 = lin & 7;
    const int slot = lin >> 3;            // 0..127
    const int qx = slot & 15;             // q-tile index
    const int grp = c8 + 8 * (slot >> 4); // 0..63 = (bh, z)
    const int bh = grp & 31;
    const int z = grp >> 5;
    const int b = bh >> 4, h = bh & 15;
    const int q0 = qx * 128;
    const int sbeg = z * (S_ / 2);

    u16* Op = Opart + (size_t)z * (B_ * L_ * E_);
    float* lp = lpart + (size_t)z * (B_ * H_ * L_);

    const u16* Kbase = Kg + (size_t)(b * S_) * E_ + h * D_;
    const u16* Vbase = Vtg + (size_t)(b * E_ + h * D_) * S_;  // rows=d, cols=s

    const int lrow = lane >> 3;        // 0..7
    const int gu = (lane & 7) ^ lrow;  // swizzled global 16B-unit

    // issue K/V tile 0 loads first (in flight during Q fragment loads)
#pragma unroll
    for (int j = 0; j < 2; ++j) {
        int c = wv * 2 + j;
        glds16(Kbase + (size_t)(sbeg + c * 8 + lrow) * E_ + gu * 8, &Ks[0][c * 512]);
        glds16(Vbase + (size_t)(c * 8 + lrow) * S_ + sbeg + gu * 8, &Vs[0][c * 512]);
    }

    // Q fragments (B-operand: col=q=lr, k=d=kk*32+qd*8..+7) direct from global.
    short8 qf[2][2];
#pragma unroll
    for (int mi = 0; mi < 2; ++mi)
#pragma unroll
        for (int kk = 0; kk < 2; ++kk)
            qf[mi][kk] = *(const short8*)(Q + (size_t)(b * L_ + q0 + wv * 32 + mi * 16 + lr) * E_ +
                                          h * D_ + kk * 32 + qd * 8);

    // constant ones B-operand (bf16 1.0 = 0x3F80) for the l-sum MFMA
    const short one_bf = (short)0x3F80;
    short8 ones8 = {one_bf, one_bf, one_bf, one_bf, one_bf, one_bf, one_bf, one_bf};

    floatx4 o_acc[2][4];
    floatx4 l4[2];
#pragma unroll
    for (int mi = 0; mi < 2; ++mi) {
#pragma unroll
        for (int nt = 0; nt < 4; ++nt) {
            floatx4 z4 = {0.f, 0.f, 0.f, 0.f};
            o_acc[mi][nt] = z4;
        }
        floatx4 z4 = {0.f, 0.f, 0.f, 0.f};
        l4[mi] = z4;
    }

    __syncthreads();  // K/V tile 0 landed

    const int NIT = (S_ / 2) / 64;  // 16

    for (int it = 0; it < NIT; ++it) {
        const int cur = it & 1;
        // prefetch next K/V tile into the other buffer (in flight during compute)
        if (it + 1 < NIT) {
            int s1 = sbeg + (it + 1) * 64;
#pragma unroll
            for (int j = 0; j < 2; ++j) {
                int c = wv * 2 + j;
                glds16(Kbase + (size_t)(s1 + c * 8 + lrow) * E_ + gu * 8, &Ks[cur ^ 1][c * 512]);
                glds16(Vbase + (size_t)(c * 8 + lrow) * S_ + s1 + gu * 8, &Vs[cur ^ 1][c * 512]);
            }
        }

        // ---- S'^T = K Q^T (swapped): D[s][q], lane holds q=lr, s=nt*16+qd*4+r ----
        floatx4 s_[2][4];
        __builtin_amdgcn_s_setprio(1);
#pragma unroll
        for (int nt = 0; nt < 4; ++nt) {
            int krow = nt * 16 + lr;
            short8 kb0 = *(const short8*)(&Ks[cur][krow * 64 + ((qd) ^ (lr & 7)) * 8]);
            short8 kb1 = *(const short8*)(&Ks[cur][krow * 64 + ((4 + qd) ^ (lr & 7)) * 8]);
#pragma unroll
            for (int mi = 0; mi < 2; ++mi) {
                floatx4 zz = {0.f, 0.f, 0.f, 0.f};
                zz = __builtin_amdgcn_mfma_f32_16x16x32_bf16(kb0, qf[mi][0], zz, 0, 0, 0);
                zz = __builtin_amdgcn_mfma_f32_16x16x32_bf16(kb1, qf[mi][1], zz, 0, 0, 0);
                s_[mi][nt] = zz;
            }
        }
        __builtin_amdgcn_s_setprio(0);

        // ---- p = exp2(s'); pack bf16 pairs; permlane exchange -> PV A-frags ----
        short8 pf[2][2];
#pragma unroll
        for (int mi = 0; mi < 2; ++mi) {
            u32 dg[4][2];
#pragma unroll
            for (int nt = 0; nt < 4; ++nt) {
                float p0 = __builtin_amdgcn_exp2f(s_[mi][nt][0]);
                float p1 = __builtin_amdgcn_exp2f(s_[mi][nt][1]);
                float p2 = __builtin_amdgcn_exp2f(s_[mi][nt][2]);
                float p3 = __builtin_amdgcn_exp2f(s_[mi][nt][3]);
                dg[nt][0] = cvt_pk_bf16(p0, p1);
                dg[nt][1] = cvt_pk_bf16(p2, p3);
            }
#pragma unroll
            for (int kk = 0; kk < 2; ++kk) {
                u32 x0 = dg[2 * kk][0], y0 = dg[2 * kk + 1][0];
                pl32swap(x0, y0);  // x0=[X0,X1,Y0,Y1] y0=[X2,X3,Y2,Y3]
                pl16swap(x0, y0);  // x0=[X0,X2,Y0,Y2] y0=[X1,X3,Y1,Y3]
                u32 x1 = dg[2 * kk][1], y1 = dg[2 * kk + 1][1];
                pl32swap(x1, y1);
                pl16swap(x1, y1);
                union { u32 d[4]; short8 v; } u;
                u.d[0] = x0; u.d[1] = x1; u.d[2] = y0; u.d[3] = y1;
                pf[mi][kk] = u.v;
            }
        }

        // ---- O += P V ; l += P * ones (row-sum via MFMA) ----
        __builtin_amdgcn_s_setprio(1);
#pragma unroll
        for (int mi = 0; mi < 2; ++mi) {
            l4[mi] = __builtin_amdgcn_mfma_f32_16x16x32_bf16(pf[mi][0], ones8, l4[mi], 0, 0, 0);
            l4[mi] = __builtin_amdgcn_mfma_f32_16x16x32_bf16(pf[mi][1], ones8, l4[mi], 0, 0, 0);
        }
#pragma unroll
        for (int nt = 0; nt < 4; ++nt) {
            int vrow = nt * 16 + lr;
            short8 vb0 = *(const short8*)(&Vs[cur][vrow * 64 + ((qd) ^ (lr & 7)) * 8]);
            short8 vb1 = *(const short8*)(&Vs[cur][vrow * 64 + ((4 + qd) ^ (lr & 7)) * 8]);
#pragma unroll
            for (int mi = 0; mi < 2; ++mi) {
                o_acc[mi][nt] = __builtin_amdgcn_mfma_f32_16x16x32_bf16(pf[mi][0], vb0, o_acc[mi][nt], 0, 0, 0);
                o_acc[mi][nt] = __builtin_amdgcn_mfma_f32_16x16x32_bf16(pf[mi][1], vb1, o_acc[mi][nt], 0, 0, 0);
            }
        }
        __builtin_amdgcn_s_setprio(0);

        __syncthreads();  // readers done with cur; prefetch into cur^1 drained
    }

    // ---- epilogue: l4[mi][r] = l for row qd*4+r (all lanes); no shuffles ----
    float linv[2][4];
#pragma unroll
    for (int mi = 0; mi < 2; ++mi) {
        if (lr == 0) {
#pragma unroll
            for (int r = 0; r < 4; ++r)
                lp[(size_t)(b * H_ + h) * L_ + q0 + wv * 32 + mi * 16 + qd * 4 + r] = l4[mi][r];
        }
#pragma unroll
        for (int r = 0; r < 4; ++r) linv[mi][r] = 1.0f / l4[mi][r];
    }

#pragma unroll
    for (int mi = 0; mi < 2; ++mi)
#pragma unroll
        for (int nt = 0; nt < 4; ++nt)
#pragma unroll
            for (int r = 0; r < 4; ++r) {
                int row = q0 + wv * 32 + mi * 16 + qd * 4 + r;
                int col = h * D_ + nt * 16 + lr;
                Op[(size_t)(b * L_ + row) * E_ + col] = f2bf(o_acc[mi][nt][r] * linv[mi][r]);
            }
}

// ---------------------------------------------------------------------------
// Output GEMM with fused split-S combine. BM=64 BN=128 BK=64, grid (8,64),
// 2 blocks/CU. LDS 48 KB. Wave tile 32x64 (acc[2][4]).
// ---------------------------------------------------------------------------
__global__ __launch_bounds__(256, 2) void out_gemm_kernel(
    const u16* __restrict__ O1, const u16* __restrict__ O2,
    const float* __restrict__ l1, const float* __restrict__ l2,
    const u16* __restrict__ WpT, const float* __restrict__ bp,
    float* __restrict__ out) {
    __shared__ __align__(16) u16 As[2][64 * 64];   // 2 x 8 KB
    __shared__ __align__(16) u16 Bs[2][128 * 64];  // 2 x 16 KB

    const int tid = threadIdx.x;
    const int lane = tid & 63;
    const int wv = tid >> 6;
    const int wm = wv >> 1, wn = wv & 1;
    const int qd = lane >> 4, lr = lane & 15;

    // XCD remap for (8 n) x (64 m): m_idx % 8 == XCD slot
    int lin = blockIdx.x + 8 * blockIdx.y;  // 0..511
    int c8 = lin & 7;
    int g = lin >> 3;                        // 0..63
    const int m_idx = c8 + 8 * (g & 7);      // 0..63
    const int n_idx = g >> 3;                // 0..7
    const int m0 = m_idx * 64, n0 = n_idx * 128;
    const int lrow = lane >> 3;
    const int gu = (lane & 7) ^ lrow;

    floatx4 acc[2][4];
#pragma unroll
    for (int i = 0; i < 2; ++i)
#pragma unroll
        for (int j = 0; j < 4; ++j) {
            floatx4 zz = {0.f, 0.f, 0.f, 0.f};
            acc[i][j] = zz;
        }

    uint4 p1[2], p2[2];
    float la_[2], lb_[2];

#define LOAD_AO(tt)                                                                \
    {                                                                              \
        _Pragma("unroll") for (int j = 0; j < 2; ++j) {                            \
            int c = wv * 2 + j;                                                    \
            int row = m0 + c * 8 + lrow;                                           \
            int col = (tt)*64 + gu * 8;                                            \
            p1[j] = *(const uint4*)(O1 + (size_t)row * E_ + col);                  \
            p2[j] = *(const uint4*)(O2 + (size_t)row * E_ + col);                  \
            int li = (row >> 11) * (H_ * L_) + (tt)*L_ + (row & (L_ - 1));         \
            la_[j] = l1[li];                                                       \
            lb_[j] = l2[li];                                                       \
        }                                                                          \
    }

#define WRITE_AO(buf)                                                              \
    {                                                                              \
        _Pragma("unroll") for (int j = 0; j < 2; ++j) {                            \
            int c = wv * 2 + j;                                                    \
            float s = 1.0f / (la_[j] + lb_[j]);                                    \
            float w1 = la_[j] * s, w2 = lb_[j] * s;                                \
            const u32* pa = (const u32*)&p1[j];                                    \
            const u32* pb = (const u32*)&p2[j];                                    \
            uint4 o;                                                               \
            u32* po = (u32*)&o;                                                    \
            _Pragma("unroll") for (int d = 0; d < 4; ++d) {                        \
                union { u32 u; float f; } x0, x1, y0, y1;                          \
                x0.u = pa[d] << 16; x1.u = pa[d] & 0xFFFF0000u;                    \
                y0.u = pb[d] << 16; y1.u = pb[d] & 0xFFFF0000u;                    \
                po[d] = cvt_pk_bf16(x0.f * w1 + y0.f * w2, x1.f * w1 + y1.f * w2); \
            }                                                                      \
            *(uint4*)(&As[buf][c * 512 + lane * 8]) = o;                           \
        }                                                                          \
    }

#define STAGE_BO(buf, kb)                                                          \
    {                                                                              \
        _Pragma("unroll") for (int j = 0; j < 4; ++j) {                            \
            int c = wv * 4 + j;                                                    \
            glds16(WpT + (size_t)(n0 + c * 8 + lrow) * E_ + (kb) + gu * 8,         \
                   &Bs[buf][c * 512]);                                             \
        }                                                                          \
    }

    LOAD_AO(0)
    STAGE_BO(0, 0)
    WRITE_AO(0)
    __syncthreads();

    for (int t = 0; t < 16; ++t) {
        const int cur = t & 1;
        if (t + 1 < 16) {
            STAGE_BO(cur ^ 1, (t + 1) * 64)
            LOAD_AO(t + 1)
        }

        short8 af[2][2], bf[4][2];
#pragma unroll
        for (int mi = 0; mi < 2; ++mi)
#pragma unroll
            for (int kk = 0; kk < 2; ++kk) {
                int row = wm * 32 + mi * 16 + lr;
                int u = (kk * 4 + qd) ^ (lr & 7);
                af[mi][kk] = *(const short8*)(&As[cur][row * 64 + u * 8]);
            }
#pragma unroll
        for (int ni = 0; ni < 4; ++ni)
#pragma unroll
            for (int kk = 0; kk < 2; ++kk) {
                int row = wn * 64 + ni * 16 + lr;
                int u = (kk * 4 + qd) ^ (lr & 7);
                bf[ni][kk] = *(const short8*)(&Bs[cur][row * 64 + u * 8]);
            }
        __builtin_amdgcn_s_setprio(1);
#pragma unroll
        for (int kk = 0; kk < 2; ++kk)
#pragma unroll
            for (int mi = 0; mi < 2; ++mi)
#pragma unroll
                for (int ni = 0; ni < 4; ++ni)
                    acc[mi][ni] = __builtin_amdgcn_mfma_f32_16x16x32_bf16(
                        af[mi][kk], bf[ni][kk], acc[mi][ni], 0, 0, 0);
        __builtin_amdgcn_s_setprio(0);

        if (t + 1 < 16) WRITE_AO(cur ^ 1)
        __syncthreads();
    }

#pragma unroll
    for (int mi = 0; mi < 2; ++mi)
#pragma unroll
        for (int ni = 0; ni < 4; ++ni) {
            int col = n0 + wn * 64 + ni * 16 + lr;
            float bv_ = bp[col];
#pragma unroll
            for (int r = 0; r < 4; ++r) {
                int row = m0 + wm * 32 + mi * 16 + qd * 4 + r;
                out[(size_t)row * E_ + col] = acc[mi][ni][r] + bv_;
            }
        }
#undef LOAD_AO
#undef WRITE_AO
#undef STAGE_BO
}

// ---------------------------------------------------------------------------
extern "C" void kernel_launch(void* const* d_in, const int* in_sizes, int n_in,
                              void* d_out, int out_size, void* d_ws, size_t ws_size,
                              hipStream_t stream) {
    const float* x   = (const float*)d_in[0];
    const float* ctx = (const float*)d_in[1];
    const float* Wq  = (const float*)d_in[2];
    const float* bq  = (const float*)d_in[3];
    const float* Wk  = (const float*)d_in[4];
    const float* bk  = (const float*)d_in[5];
    const float* Wv  = (const float*)d_in[6];
    const float* bv  = (const float*)d_in[7];
    const float* Wp  = (const float*)d_in[8];
    const float* bp  = (const float*)d_in[9];
    float* out = (float*)d_out;

    // workspace (u16 elems): WqT..WpT 4x1M | Qb 4M | Kb 4M | Vtb 4M |
    // Xb 4M | Cb 4M (Xb/Cb reused as Opart[0/1] after projections) | lpart
    u16* WqT = (u16*)d_ws;
    u16* WkT = WqT + 1048576;
    u16* WvT = WkT + 1048576;
    u16* WpT = WvT + 1048576;
    u16* Qb  = WpT + 1048576;
    u16* Kb  = Qb + 4194304;
    u16* Vtb = Kb + 4194304;
    u16* Xb  = Vtb + 4194304;
    u16* Cb  = Xb + 4194304;
    u16* Opart = Xb;  // overlays Xb/Cb (dead after projections)
    float* lpart = (float*)(Cb + 4194304);
    (void)ws_size; (void)in_sizes; (void)n_in; (void)out_size;

    prep_kernel<<<dim3(8192), 256, 0, stream>>>(
        x, ctx, Xb, Cb, Wq, Wk, Wv, Wp, WqT, WkT, WvT, WpT);

    qkv_gemm_kernel<<<dim3(8, 32, 3), 256, 0, stream>>>(
        Xb, Cb, WqT, WkT, WvT, bq, bk, bv, Qb, Kb, Vtb);

    flash_attn_kernel<<<dim3(L_ / 128, B_ * H_, 2), 256, 0, stream>>>(
        Qb, Kb, Vtb, Opart, lpart);

    out_gemm_kernel<<<dim3(8, 64), 256, 0, stream>>>(
        Opart, Opart + 4194304, lpart, lpart + B_ * H_ * L_, WpT, bp, out);
}